// Round 1
// baseline (486.707 us; speedup 1.0000x reference)
//
#include <hip/hip_runtime.h>
#include <hip/hip_bf16.h>
#include <math.h>

#define B_ 4
#define N_ 1370
#define C_ 1024
#define H_ 16
#define DH_ 64
#define HID_ 4096
#define M_ (B_*N_)      // 5480
#define MPAD 5504       // 43*128

typedef short v8s __attribute__((ext_vector_type(8)));
typedef short v4s16 __attribute__((ext_vector_type(4)));
typedef float v4f __attribute__((ext_vector_type(4)));

__device__ __forceinline__ short f2bf(float x) {
  union { float f; unsigned u; } a; a.f = x;
  unsigned r = (a.u + 0x7fffu + ((a.u >> 16) & 1u)) >> 16;
  return (short)r;
}

__device__ __forceinline__ void gl_lds16(const void* g, void* l) {
  __builtin_amdgcn_global_load_lds(
      (const __attribute__((address_space(1))) unsigned int*)g,
      (__attribute__((address_space(3))) unsigned int*)l, 16, 0, 0);
}

// ---- cast all four weight matrices f32 -> bf16 into one contiguous ws region
__global__ __launch_bounds__(256) void cast_w(const float* __restrict__ wq, const float* __restrict__ wp,
                                              const float* __restrict__ w1, const float* __restrict__ w2,
                                              short* __restrict__ out) {
  int i = blockIdx.x * 256 + threadIdx.x;
  int e = i << 2;
  const float* src; int off;
  if (e < 3145728)      { src = wq; off = e; }
  else if (e < 4194304) { src = wp; off = e - 3145728; }
  else if (e < 8388608) { src = w1; off = e - 4194304; }
  else                  { src = w2; off = e - 8388608; }
  float4 v = *reinterpret_cast<const float4*>(src + off);
  v4s16 o;
  o[0] = f2bf(v.x); o[1] = f2bf(v.y); o[2] = f2bf(v.z); o[3] = f2bf(v.w);
  *reinterpret_cast<v4s16*>(out + e) = o;
}

// ---- layernorm (f32 in, bf16 out), one block per row, pad rows -> zeros
__global__ __launch_bounds__(256) void ln_k(const float* __restrict__ x, const float* __restrict__ g,
                                            const float* __restrict__ bt, short* __restrict__ out, int mreal) {
  int row = blockIdx.x, t = threadIdx.x;
  short* orow = out + (size_t)row * C_;
  if (row >= mreal) {
    v4s16 z = {0,0,0,0};
    reinterpret_cast<v4s16*>(orow)[t] = z;
    return;
  }
  float4 v = reinterpret_cast<const float4*>(x + (size_t)row * C_)[t];
  float s = v.x + v.y + v.z + v.w;
  float q = v.x*v.x + v.y*v.y + v.z*v.z + v.w*v.w;
#pragma unroll
  for (int m = 1; m < 64; m <<= 1) { s += __shfl_xor(s, m); q += __shfl_xor(q, m); }
  __shared__ float sb[8];
  int w = t >> 6;
  if ((t & 63) == 0) { sb[w] = s; sb[4 + w] = q; }
  __syncthreads();
  s = sb[0] + sb[1] + sb[2] + sb[3];
  q = sb[4] + sb[5] + sb[6] + sb[7];
  float mean = s * (1.f / C_);
  float rstd = rsqrtf(q * (1.f / C_) - mean * mean + 1e-5f);
  float4 gv = reinterpret_cast<const float4*>(g)[t];
  float4 bv = reinterpret_cast<const float4*>(bt)[t];
  v4s16 o;
  o[0] = f2bf((v.x - mean) * rstd * gv.x + bv.x);
  o[1] = f2bf((v.y - mean) * rstd * gv.y + bv.y);
  o[2] = f2bf((v.z - mean) * rstd * gv.z + bv.z);
  o[3] = f2bf((v.w - mean) * rstd * gv.w + bv.w);
  reinterpret_cast<v4s16*>(orow)[t] = o;
}

// ---- 128x128-tile bf16 GEMM, C[r][c] = sum_k A[r][k]*Bw[c][k] (+ epilogue)
// MODE 0: obf = bf16( (v+bias) * (col<1024 ? 0.125 : 1) )        [QKV]
// MODE 1: of32 = resid + gamma*(v+bias)   (rows < mreal)         [proj / fc2]
// MODE 2: obf = bf16( gelu_exact(v+bias) )                       [fc1]
template<int MODE>
__global__ __launch_bounds__(256) void gemm_k(
    const short* __restrict__ A, const short* __restrict__ Bw,
    const float* __restrict__ bias, const float* __restrict__ resid,
    const float* __restrict__ gamma, short* __restrict__ obf,
    float* __restrict__ of32, int K, int Nc, int mreal)
{
  __shared__ short As[128 * 32];
  __shared__ short Bs[128 * 32];
  int tid = threadIdx.x;
  int lane = tid & 63, wave = tid >> 6;
  int l15 = lane & 15, lhi = lane >> 4;
  int tn = blockIdx.x, tm = blockIdx.y;
  int wr = wave >> 1, wc = wave & 1;

  v4f acc[4][4];
#pragma unroll
  for (int m = 0; m < 4; m++)
#pragma unroll
    for (int n = 0; n < 4; n++) acc[m][n] = v4f{0.f, 0.f, 0.f, 0.f};

  // staging: thread -> (row = wave*16 + lane/4 [+64], chunk = lane%4), source chunk XOR-swizzled
  int lrow = lane >> 2, lch = lane & 3;
  int scol = ((lch ^ ((lrow >> 1) & 3)) << 3);
  const short* Ag = A + (size_t)(tm * 128 + wave * 16 + lrow) * K + scol;
  const short* Bg = Bw + (size_t)(tn * 128 + wave * 16 + lrow) * K + scol;
  short* Asw = As + (wave * 16) * 32;
  short* Bsw = Bs + (wave * 16) * 32;
  int fch = ((lhi ^ ((l15 >> 1) & 3)) << 3);   // swizzled read chunk

  int kT = K >> 5;
  for (int kt = 0; kt < kT; ++kt) {
    int k0 = kt << 5;
    __syncthreads();
    gl_lds16(Ag + k0, Asw);
    gl_lds16(Ag + (size_t)64 * K + k0, Asw + 64 * 32);
    gl_lds16(Bg + k0, Bsw);
    gl_lds16(Bg + (size_t)64 * K + k0, Bsw + 64 * 32);
    __syncthreads();
    v8s af[4], bfr[4];
#pragma unroll
    for (int m = 0; m < 4; m++)
      af[m] = *reinterpret_cast<const v8s*>(As + (wr * 64 + m * 16 + l15) * 32 + fch);
#pragma unroll
    for (int n = 0; n < 4; n++)
      bfr[n] = *reinterpret_cast<const v8s*>(Bs + (wc * 64 + n * 16 + l15) * 32 + fch);
#pragma unroll
    for (int m = 0; m < 4; m++)
#pragma unroll
      for (int n = 0; n < 4; n++)
        acc[m][n] = __builtin_amdgcn_mfma_f32_16x16x32_bf16(af[m], bfr[n], acc[m][n], 0, 0, 0);
  }

  int row0 = tm * 128 + wr * 64 + (lhi << 2);
  int col0 = tn * 128 + wc * 64 + l15;
#pragma unroll
  for (int m = 0; m < 4; m++) {
#pragma unroll
    for (int n = 0; n < 4; n++) {
      int gc = col0 + n * 16;
      float bb = bias[gc];
      float gm = (MODE == 1) ? gamma[gc] : 0.f;
#pragma unroll
      for (int r = 0; r < 4; r++) {
        int gr = row0 + m * 16 + r;
        float v = acc[m][n][r] + bb;
        if (MODE == 0) {
          float sc = (gc < 1024) ? 0.125f : 1.0f;
          obf[(size_t)gr * Nc + gc] = f2bf(v * sc);
        } else if (MODE == 2) {
          obf[(size_t)gr * Nc + gc] = f2bf(0.5f * v * (1.f + erff(v * 0.70710678f)));
        } else {
          if (gr < mreal) of32[(size_t)gr * Nc + gc] = resid[(size_t)gr * Nc + gc] + gm * v;
        }
      }
    }
  }
}

// ---- flash attention: block = (qtile of 64 rows) x (b,h); 4 waves x 16 q-rows
__global__ __launch_bounds__(256) void attn_k(const short* __restrict__ qkv, short* __restrict__ o)
{
  int qt = blockIdx.x, bh = blockIdx.y;
  int b = bh >> 4, h = bh & 15;
  int tid = threadIdx.x;
  int lane = tid & 63, wave = tid >> 6;
  int l15 = lane & 15, lhi = lane >> 4;

  __shared__ short Ks[32 * 64];   // [kv][d], chunk ^= (kv&7)
  __shared__ short Vt[64 * 32];   // [d][kv], chunk ^= ((d>>1)&3)
  __shared__ short Ps[4 * 16 * 32]; // per-wave P tile, chunk ^= ((q>>1)&3)

  int qrow = qt * 64 + wave * 16 + l15;
  int qc = qrow < N_ ? qrow : N_ - 1;
  const short* qp = qkv + (size_t)(b * N_ + qc) * 3072 + h * 64;
  v8s q0 = *reinterpret_cast<const v8s*>(qp + lhi * 8);
  v8s q1 = *reinterpret_cast<const v8s*>(qp + 32 + lhi * 8);

  float mx[4], ls[4];
  v4f oacc[4];
#pragma unroll
  for (int r = 0; r < 4; r++) { mx[r] = -INFINITY; ls[r] = 0.f; }
#pragma unroll
  for (int d = 0; d < 4; d++) oacc[d] = v4f{0.f, 0.f, 0.f, 0.f};

  int krow = tid >> 3, kch = tid & 7;
  const short* kg = qkv + (size_t)(b * N_ + krow) * 3072 + 1024 + h * 64 + ((kch ^ (krow & 7)) << 3);
  short* Kw = Ks + wave * 512;
  int vkv = tid & 31, vd0 = (tid >> 5) << 3;
  const short* vg = qkv + (size_t)(b * N_ + vkv) * 3072 + 2048 + h * 64 + vd0;

  short* Pw = Ps + (wave << 9);
  int prs = (l15 >> 1) & 3;

  const int NT = (N_ + 31) / 32;   // 43
  for (int t = 0; t < NT; ++t) {
    int kv0 = t << 5;
    __syncthreads();
    gl_lds16(kg + (size_t)kv0 * 3072, Kw);
    v8s vv = *reinterpret_cast<const v8s*>(vg + (size_t)kv0 * 3072);
#pragma unroll
    for (int j = 0; j < 8; j++) {
      int d = vd0 + j;
      Vt[d * 32 + (((vkv >> 3) ^ ((d >> 1) & 3)) << 3) + (vkv & 7)] = vv[j];
    }
    __syncthreads();

    // S = Q K^T  (two 16-col halves), K contraction d=64 in two mfma
    v4f s0 = v4f{0.f,0.f,0.f,0.f}, s1 = v4f{0.f,0.f,0.f,0.f};
#pragma unroll
    for (int half = 0; half < 2; ++half) {
      int c = half * 4 + lhi;
      int ra = l15, rb = 16 + l15;
      v8s ka = *reinterpret_cast<const v8s*>(Ks + ra * 64 + ((c ^ (ra & 7)) << 3));
      v8s kb = *reinterpret_cast<const v8s*>(Ks + rb * 64 + ((c ^ (rb & 7)) << 3));
      v8s qh = half ? q1 : q0;
      s0 = __builtin_amdgcn_mfma_f32_16x16x32_bf16(qh, ka, s0, 0, 0, 0);
      s1 = __builtin_amdgcn_mfma_f32_16x16x32_bf16(qh, kb, s1, 0, 0, 0);
    }
    bool msk0 = (kv0 + l15) >= N_;
    bool msk1 = (kv0 + 16 + l15) >= N_;
#pragma unroll
    for (int r = 0; r < 4; r++) {
      if (msk0) s0[r] = -1e30f;
      if (msk1) s1[r] = -1e30f;
    }
    float p0[4], p1[4];
#pragma unroll
    for (int r = 0; r < 4; r++) {
      float pm = fmaxf(s0[r], s1[r]);
#pragma unroll
      for (int mm = 1; mm < 16; mm <<= 1) pm = fmaxf(pm, __shfl_xor(pm, mm));
      float mn = fmaxf(mx[r], pm);
      float sc = __expf(mx[r] - mn);
      mx[r] = mn;
      float e0 = __expf(s0[r] - mn);
      float e1 = __expf(s1[r] - mn);
      float rsum = e0 + e1;
#pragma unroll
      for (int mm = 1; mm < 16; mm <<= 1) rsum += __shfl_xor(rsum, mm);
      ls[r] = ls[r] * sc + rsum;
      p0[r] = e0; p1[r] = e1;
#pragma unroll
      for (int d = 0; d < 4; d++) oacc[d][r] *= sc;
    }
    // P (C/D layout) -> LDS -> A layout
#pragma unroll
    for (int r = 0; r < 4; r++) {
      int prow = (lhi << 2) + r;
      int sel = (prow >> 1) & 3;
      Pw[prow * 32 + ((((l15 >> 3)) ^ sel) << 3) + (l15 & 7)] = f2bf(p0[r]);
      Pw[prow * 32 + (((2 + (l15 >> 3)) ^ sel) << 3) + (l15 & 7)] = f2bf(p1[r]);
    }
    v8s pa = *reinterpret_cast<const v8s*>(Pw + l15 * 32 + ((lhi ^ prs) << 3));
#pragma unroll
    for (int dc = 0; dc < 4; ++dc) {
      int vrow = dc * 16 + l15;
      v8s vb = *reinterpret_cast<const v8s*>(Vt + vrow * 32 + ((lhi ^ ((vrow >> 1) & 3)) << 3));
      oacc[dc] = __builtin_amdgcn_mfma_f32_16x16x32_bf16(pa, vb, oacc[dc], 0, 0, 0);
    }
  }

#pragma unroll
  for (int r = 0; r < 4; r++) {
    int qg = qt * 64 + wave * 16 + (lhi << 2) + r;
    if (qg < N_) {
      float inv = 1.f / ls[r];
      short* op = o + (size_t)(b * N_ + qg) * 1024 + h * 64 + l15;
#pragma unroll
      for (int dc = 0; dc < 4; dc++) op[dc * 16] = f2bf(oacc[dc][r] * inv);
    }
  }
}

extern "C" void kernel_launch(void* const* d_in, const int* in_sizes, int n_in,
                              void* d_out, int out_size, void* d_ws, size_t ws_size,
                              hipStream_t stream) {
  const float* x     = (const float*)d_in[0];
  const float* ln1g  = (const float*)d_in[1];
  const float* ln1b  = (const float*)d_in[2];
  const float* wqkv  = (const float*)d_in[3];
  const float* bqkv  = (const float*)d_in[4];
  const float* wproj = (const float*)d_in[5];
  const float* bproj = (const float*)d_in[6];
  const float* g1    = (const float*)d_in[7];
  const float* ln2g  = (const float*)d_in[8];
  const float* ln2b  = (const float*)d_in[9];
  const float* wfc1  = (const float*)d_in[10];
  const float* bfc1  = (const float*)d_in[11];
  const float* wfc2  = (const float*)d_in[12];
  const float* bfc2  = (const float*)d_in[13];
  const float* g2    = (const float*)d_in[14];
  float* out = (float*)d_out;

  char* p = (char*)d_ws;
  short* wb   = (short*)(p);                 // bf16 weights, 25,165,824 B
  short* h1   = (short*)(p + 25165824);      // bf16 [MPAD][1024]
  short* qkvb = (short*)(p + 36438016);      // bf16 [MPAD][3072]
  short* ob   = (short*)(p + 70254592);      // bf16 [MPAD][1024]
  float* x2   = (float*)(p + 81526784);      // f32  [MPAD][1024]  (end 104,071,168)
  short* h2   = ob;                          // reuse (proj consumed ob before LN2)
  short* mlp  = h1;                          // reuse h1+qkvb region: [MPAD][4096] bf16

  cast_w<<<12288, 256, 0, stream>>>(wqkv, wproj, wfc1, wfc2, wb);
  ln_k<<<MPAD, 256, 0, stream>>>(x, ln1g, ln1b, h1, M_);
  gemm_k<0><<<dim3(24, 43), 256, 0, stream>>>(h1, wb, bqkv, nullptr, nullptr, qkvb, nullptr, 1024, 3072, M_);
  attn_k<<<dim3(22, 64), 256, 0, stream>>>(qkvb, ob);
  gemm_k<1><<<dim3(8, 43), 256, 0, stream>>>(ob, wb + 3145728, bproj, x, g1, nullptr, x2, 1024, 1024, M_);
  ln_k<<<MPAD, 256, 0, stream>>>(x2, ln2g, ln2b, h2, M_);
  gemm_k<2><<<dim3(32, 43), 256, 0, stream>>>(h2, wb + 4194304, bfc1, nullptr, nullptr, mlp, nullptr, 1024, 4096, M_);
  gemm_k<1><<<dim3(8, 43), 256, 0, stream>>>(mlp, wb + 8388608, bfc2, x2, g2, nullptr, out, 4096, 1024, M_);
}

// Round 2
// 407.615 us; speedup vs baseline: 1.1940x; 1.1940x over previous
//
#include <hip/hip_runtime.h>
#include <hip/hip_bf16.h>
#include <math.h>

#define B_ 4
#define N_ 1370
#define C_ 1024
#define H_ 16
#define DH_ 64
#define HID_ 4096
#define M_ (B_*N_)      // 5480
#define MPAD 5504       // 43*128

typedef short v8s __attribute__((ext_vector_type(8)));
typedef short v4s16 __attribute__((ext_vector_type(4)));
typedef float v4f __attribute__((ext_vector_type(4)));
typedef float v16f __attribute__((ext_vector_type(16)));

__device__ __forceinline__ short f2bf(float x) {
  union { float f; unsigned u; } a; a.f = x;
  unsigned r = (a.u + 0x7fffu + ((a.u >> 16) & 1u)) >> 16;
  return (short)r;
}

__device__ __forceinline__ void gl_lds16(const void* g, void* l) {
  __builtin_amdgcn_global_load_lds(
      (const __attribute__((address_space(1))) unsigned int*)g,
      (__attribute__((address_space(3))) unsigned int*)l, 16, 0, 0);
}

// ---- cast all four weight matrices f32 -> bf16 into one contiguous ws region
__global__ __launch_bounds__(256) void cast_w(const float* __restrict__ wq, const float* __restrict__ wp,
                                              const float* __restrict__ w1, const float* __restrict__ w2,
                                              short* __restrict__ out) {
  int i = blockIdx.x * 256 + threadIdx.x;
  int e = i << 2;
  const float* src; int off;
  if (e < 3145728)      { src = wq; off = e; }
  else if (e < 4194304) { src = wp; off = e - 3145728; }
  else if (e < 8388608) { src = w1; off = e - 4194304; }
  else                  { src = w2; off = e - 8388608; }
  float4 v = *reinterpret_cast<const float4*>(src + off);
  v4s16 o;
  o[0] = f2bf(v.x); o[1] = f2bf(v.y); o[2] = f2bf(v.z); o[3] = f2bf(v.w);
  *reinterpret_cast<v4s16*>(out + e) = o;
}

// ---- layernorm (f32 in, bf16 out), one block per row, pad rows -> zeros
__global__ __launch_bounds__(256) void ln_k(const float* __restrict__ x, const float* __restrict__ g,
                                            const float* __restrict__ bt, short* __restrict__ out, int mreal) {
  int row = blockIdx.x, t = threadIdx.x;
  short* orow = out + (size_t)row * C_;
  if (row >= mreal) {
    v4s16 z = {0,0,0,0};
    reinterpret_cast<v4s16*>(orow)[t] = z;
    return;
  }
  float4 v = reinterpret_cast<const float4*>(x + (size_t)row * C_)[t];
  float s = v.x + v.y + v.z + v.w;
  float q = v.x*v.x + v.y*v.y + v.z*v.z + v.w*v.w;
#pragma unroll
  for (int m = 1; m < 64; m <<= 1) { s += __shfl_xor(s, m); q += __shfl_xor(q, m); }
  __shared__ float sb[8];
  int w = t >> 6;
  if ((t & 63) == 0) { sb[w] = s; sb[4 + w] = q; }
  __syncthreads();
  s = sb[0] + sb[1] + sb[2] + sb[3];
  q = sb[4] + sb[5] + sb[6] + sb[7];
  float mean = s * (1.f / C_);
  float rstd = rsqrtf(q * (1.f / C_) - mean * mean + 1e-5f);
  float4 gv = reinterpret_cast<const float4*>(g)[t];
  float4 bv = reinterpret_cast<const float4*>(bt)[t];
  v4s16 o;
  o[0] = f2bf((v.x - mean) * rstd * gv.x + bv.x);
  o[1] = f2bf((v.y - mean) * rstd * gv.y + bv.y);
  o[2] = f2bf((v.z - mean) * rstd * gv.z + bv.z);
  o[3] = f2bf((v.w - mean) * rstd * gv.w + bv.w);
  reinterpret_cast<v4s16*>(orow)[t] = o;
}

// ---- 128x128-tile bf16 GEMM, C[r][c] = sum_k A[r][k]*Bw[c][k] (+ epilogue)
// MODE 0: obf = bf16( (v+bias) * (col<1024 ? 0.125*log2e : 1) )   [QKV]
// MODE 1: of32 = resid + gamma*(v+bias)   (rows < mreal)          [proj / fc2]
// MODE 2: obf = bf16( gelu_exact(v+bias) )                        [fc1]
template<int MODE>
__global__ __launch_bounds__(256) void gemm_k(
    const short* __restrict__ A, const short* __restrict__ Bw,
    const float* __restrict__ bias, const float* __restrict__ resid,
    const float* __restrict__ gamma, short* __restrict__ obf,
    float* __restrict__ of32, int K, int Nc, int mreal)
{
  __shared__ short As[128 * 32];
  __shared__ short Bs[128 * 32];
  int tid = threadIdx.x;
  int lane = tid & 63, wave = tid >> 6;
  int l15 = lane & 15, lhi = lane >> 4;
  int tn = blockIdx.x, tm = blockIdx.y;
  int wr = wave >> 1, wc = wave & 1;

  v4f acc[4][4];
#pragma unroll
  for (int m = 0; m < 4; m++)
#pragma unroll
    for (int n = 0; n < 4; n++) acc[m][n] = v4f{0.f, 0.f, 0.f, 0.f};

  int lrow = lane >> 2, lch = lane & 3;
  int scol = ((lch ^ ((lrow >> 1) & 3)) << 3);
  const short* Ag = A + (size_t)(tm * 128 + wave * 16 + lrow) * K + scol;
  const short* Bg = Bw + (size_t)(tn * 128 + wave * 16 + lrow) * K + scol;
  short* Asw = As + (wave * 16) * 32;
  short* Bsw = Bs + (wave * 16) * 32;
  int fch = ((lhi ^ ((l15 >> 1) & 3)) << 3);

  int kT = K >> 5;
  for (int kt = 0; kt < kT; ++kt) {
    int k0 = kt << 5;
    __syncthreads();
    gl_lds16(Ag + k0, Asw);
    gl_lds16(Ag + (size_t)64 * K + k0, Asw + 64 * 32);
    gl_lds16(Bg + k0, Bsw);
    gl_lds16(Bg + (size_t)64 * K + k0, Bsw + 64 * 32);
    __syncthreads();
    v8s af[4], bfr[4];
#pragma unroll
    for (int m = 0; m < 4; m++)
      af[m] = *reinterpret_cast<const v8s*>(As + (wr * 64 + m * 16 + l15) * 32 + fch);
#pragma unroll
    for (int n = 0; n < 4; n++)
      bfr[n] = *reinterpret_cast<const v8s*>(Bs + (wc * 64 + n * 16 + l15) * 32 + fch);
#pragma unroll
    for (int m = 0; m < 4; m++)
#pragma unroll
      for (int n = 0; n < 4; n++)
        acc[m][n] = __builtin_amdgcn_mfma_f32_16x16x32_bf16(af[m], bfr[n], acc[m][n], 0, 0, 0);
  }

  int row0 = tm * 128 + wr * 64 + (lhi << 2);
  int col0 = tn * 128 + wc * 64 + l15;
#pragma unroll
  for (int m = 0; m < 4; m++) {
#pragma unroll
    for (int n = 0; n < 4; n++) {
      int gc = col0 + n * 16;
      float bb = bias[gc];
      float gm = (MODE == 1) ? gamma[gc] : 0.f;
#pragma unroll
      for (int r = 0; r < 4; r++) {
        int gr = row0 + m * 16 + r;
        float v = acc[m][n][r] + bb;
        if (MODE == 0) {
          float sc = (gc < 1024) ? 0.18033688011112042f : 1.0f;  // 0.125 * log2(e)
          obf[(size_t)gr * Nc + gc] = f2bf(v * sc);
        } else if (MODE == 2) {
          obf[(size_t)gr * Nc + gc] = f2bf(0.5f * v * (1.f + erff(v * 0.70710678f)));
        } else {
          if (gr < mreal) of32[(size_t)gr * Nc + gc] = resid[(size_t)gr * Nc + gc] + gm * v;
        }
      }
    }
  }
}

// ---- P fragment builder: 8 f32 (C/D-layout regs) -> A-frag via cvt_pk + permlane32_swap (T12)
__device__ __forceinline__ v8s pack_swap(const float* p) {
  unsigned w0, w1, w2, w3;
  asm("v_cvt_pk_bf16_f32 %0, %1, %2" : "=v"(w0) : "v"(p[0]), "v"(p[1]));
  asm("v_cvt_pk_bf16_f32 %0, %1, %2" : "=v"(w1) : "v"(p[2]), "v"(p[3]));
  asm("v_cvt_pk_bf16_f32 %0, %1, %2" : "=v"(w2) : "v"(p[4]), "v"(p[5]));
  asm("v_cvt_pk_bf16_f32 %0, %1, %2" : "=v"(w3) : "v"(p[6]), "v"(p[7]));
  asm("v_permlane32_swap_b32 %0, %1" : "+v"(w0), "+v"(w2));
  asm("v_permlane32_swap_b32 %0, %1" : "+v"(w1), "+v"(w3));
  union { unsigned u[4]; v8s s; } r;
  r.u[0] = w0; r.u[1] = w1; r.u[2] = w2; r.u[3] = w3;
  return r.s;
}

// ---- flash attention, swapped-QK^T 32x32x16 structure (m214 style)
// block: 4 waves x 32 q-rows = 128 q; KV tiles of 64. grid (ceil(N/128), B*H)
__global__ __launch_bounds__(256) void attn_k(const short* __restrict__ qkv, short* __restrict__ o)
{
  int qt = blockIdx.x, bh = blockIdx.y;
  int b = bh >> 4, h = bh & 15;
  int tid = threadIdx.x;
  int lane = tid & 63, wave = tid >> 6;
  int l31 = lane & 31, hi = lane >> 5;

  __shared__ short Ks[64 * 64];   // [kv][d], 16B-chunk ^= (kv&7), filled linearly by gl_lds w/ pre-swizzled src
  __shared__ short Vt[64 * 64];   // [d][kv], 8-elem chunk ^= ((d>>1)&7)

  // Q fragments: lane q = l31, B-frag i: Q[q][16i + 8*hi .. +8]  (q pre-scaled by 0.125*log2e)
  int qrow = qt * 128 + wave * 32 + l31;
  int qc = qrow < N_ ? qrow : N_ - 1;
  const short* qp = qkv + (size_t)(b * N_ + qc) * 3072 + h * 64;
  v8s qf[4];
#pragma unroll
  for (int i = 0; i < 4; i++) qf[i] = *reinterpret_cast<const v8s*>(qp + i * 16 + hi * 8);

  v16f oa0, oa1;
#pragma unroll
  for (int r = 0; r < 16; r++) { oa0[r] = 0.f; oa1[r] = 0.f; }
  float m = -INFINITY, ls = 0.f;

  // K staging map: slot = wave*64+lane (call A) / +256 (call B); kv = slot>>3, chunk = lane&7
  int kvA = wave * 8 + (lane >> 3);
  int kchunk = ((lane & 7) ^ (kvA & 7)) << 3;       // element offset of swizzled 8-elem chunk
  short* ldsKA = Ks + wave * 512;
  short* ldsKB = Ks + 2048 + wave * 512;

  // V staging map: thread -> kv = tid&63, d0 = (tid>>6)*16 (16 d's via two v8s)
  int vkv = tid & 63, vd0 = (tid >> 6) << 4;

  const int NT = (N_ + 63) / 64;   // 22
  for (int t = 0; t < NT; ++t) {
    int kv0 = t * 64;
    int ra = kv0 + kvA;      ra = ra < N_ ? ra : N_ - 1;
    int rb = kv0 + kvA + 32; rb = rb < N_ ? rb : N_ - 1;
    int rv = kv0 + vkv;      rv = rv < N_ ? rv : N_ - 1;
    const short* vsrc = qkv + (size_t)(b * N_ + rv) * 3072 + 2048 + h * 64 + vd0;
    v8s va = *reinterpret_cast<const v8s*>(vsrc);
    v8s vb2 = *reinterpret_cast<const v8s*>(vsrc + 8);
    __syncthreads();
    gl_lds16(qkv + (size_t)(b * N_ + ra) * 3072 + 1024 + h * 64 + kchunk, ldsKA);
    gl_lds16(qkv + (size_t)(b * N_ + rb) * 3072 + 1024 + h * 64 + kchunk, ldsKB);
#pragma unroll
    for (int j = 0; j < 8; j++) {
      int d = vd0 + j;
      Vt[d * 64 + (((vkv >> 3) ^ ((d >> 1) & 7)) << 3) + (vkv & 7)] = va[j];
      int d2 = d + 8;
      Vt[d2 * 64 + (((vkv >> 3) ^ ((d2 >> 1) & 7)) << 3) + (vkv & 7)] = vb2[j];
    }
    __syncthreads();

    // S^T = K Q^T : A = K rows (kv = l31 [+32]), B = Q; acc over d in 4 mfma
    v16f s0, s1;
#pragma unroll
    for (int r = 0; r < 16; r++) { s0[r] = 0.f; s1[r] = 0.f; }
#pragma unroll
    for (int i = 0; i < 4; i++) {
      int c0 = ((2 * i + hi) ^ (l31 & 7)) << 3;
      v8s ka = *reinterpret_cast<const v8s*>(Ks + l31 * 64 + c0);
      v8s kb = *reinterpret_cast<const v8s*>(Ks + (32 + l31) * 64 + c0);
      s0 = __builtin_amdgcn_mfma_f32_32x32x16_bf16(ka, qf[i], s0, 0, 0, 0);
      s1 = __builtin_amdgcn_mfma_f32_32x32x16_bf16(kb, qf[i], s1, 0, 0, 0);
    }

    if (kv0 + 64 > N_) {
#pragma unroll
      for (int r = 0; r < 16; r++) {
        int crow = (r & 3) + 8 * (r >> 2) + 4 * hi;
        if (kv0 + crow >= N_) s0[r] = -1e30f;
        if (kv0 + 32 + crow >= N_) s1[r] = -1e30f;
      }
    }

    // row max over 32 own values + partner half
    float pmax = s0[0];
#pragma unroll
    for (int r = 1; r < 16; r++) pmax = fmaxf(pmax, s0[r]);
#pragma unroll
    for (int r = 0; r < 16; r++) pmax = fmaxf(pmax, s1[r]);
    pmax = fmaxf(pmax, __shfl_xor(pmax, 32));

    // defer-max (T13): rescale only when the running max grew by > 11 (exp2 domain)
    if (!__all(pmax <= m + 11.0f)) {
      float mn = fmaxf(m, pmax);
      float scf = exp2f(m - mn);
      m = mn;
#pragma unroll
      for (int r = 0; r < 16; r++) {
        int crow = (r & 3) + 8 * (r >> 2) + 4 * hi;
        float sv = __shfl(scf, crow);
        oa0[r] *= sv; oa1[r] *= sv;
      }
      ls *= scf;
    }

    float p0[16], p1[16];
    float psum = 0.f;
#pragma unroll
    for (int r = 0; r < 16; r++) { p0[r] = exp2f(s0[r] - m); psum += p0[r]; }
#pragma unroll
    for (int r = 0; r < 16; r++) { p1[r] = exp2f(s1[r] - m); psum += p1[r]; }
    psum += __shfl_xor(psum, 32);
    ls += psum;

    // P -> bf16 A-frags (kv chunks of 16)
    v8s pa0 = pack_swap(p0), pa1 = pack_swap(p0 + 8), pa2 = pack_swap(p1), pa3 = pack_swap(p1 + 8);

    // O += P V : B-frag from Vt[d][kv], d = l31 (+32), kv chunk = 2i+hi (swizzled)
#pragma unroll
    for (int i = 0; i < 4; i++) {
      v8s pai = (i == 0) ? pa0 : (i == 1) ? pa1 : (i == 2) ? pa2 : pa3;
      int cc = ((2 * i + hi) ^ ((l31 >> 1) & 7)) << 3;
      v8s v0f = *reinterpret_cast<const v8s*>(Vt + l31 * 64 + cc);
      v8s v1f = *reinterpret_cast<const v8s*>(Vt + (32 + l31) * 64 + cc);
      oa0 = __builtin_amdgcn_mfma_f32_32x32x16_bf16(pai, v0f, oa0, 0, 0, 0);
      oa1 = __builtin_amdgcn_mfma_f32_32x32x16_bf16(pai, v1f, oa1, 0, 0, 0);
    }
  }

  float inv = 1.f / ls;
#pragma unroll
  for (int r = 0; r < 16; r++) {
    int crow = (r & 3) + 8 * (r >> 2) + 4 * hi;
    float iv = __shfl(inv, crow);
    int qg = qt * 128 + wave * 32 + crow;
    if (qg < N_) {
      size_t base = (size_t)(b * N_ + qg) * 1024 + h * 64;
      o[base + l31] = f2bf(oa0[r] * iv);
      o[base + 32 + l31] = f2bf(oa1[r] * iv);
    }
  }
}

extern "C" void kernel_launch(void* const* d_in, const int* in_sizes, int n_in,
                              void* d_out, int out_size, void* d_ws, size_t ws_size,
                              hipStream_t stream) {
  const float* x     = (const float*)d_in[0];
  const float* ln1g  = (const float*)d_in[1];
  const float* ln1b  = (const float*)d_in[2];
  const float* wqkv  = (const float*)d_in[3];
  const float* bqkv  = (const float*)d_in[4];
  const float* wproj = (const float*)d_in[5];
  const float* bproj = (const float*)d_in[6];
  const float* g1    = (const float*)d_in[7];
  const float* ln2g  = (const float*)d_in[8];
  const float* ln2b  = (const float*)d_in[9];
  const float* wfc1  = (const float*)d_in[10];
  const float* bfc1  = (const float*)d_in[11];
  const float* wfc2  = (const float*)d_in[12];
  const float* bfc2  = (const float*)d_in[13];
  const float* g2    = (const float*)d_in[14];
  float* out = (float*)d_out;

  char* p = (char*)d_ws;
  short* wb   = (short*)(p);                 // bf16 weights, 25,165,824 B
  short* h1   = (short*)(p + 25165824);      // bf16 [MPAD][1024]
  short* qkvb = (short*)(p + 36438016);      // bf16 [MPAD][3072]
  short* ob   = (short*)(p + 70254592);      // bf16 [MPAD][1024]
  float* x2   = (float*)(p + 81526784);      // f32  [MPAD][1024]  (end 104,071,168)
  short* h2   = ob;                          // reuse (proj consumed ob before LN2)
  short* mlp  = h1;                          // reuse h1+qkvb region: [MPAD][4096] bf16

  cast_w<<<12288, 256, 0, stream>>>(wqkv, wproj, wfc1, wfc2, wb);
  ln_k<<<MPAD, 256, 0, stream>>>(x, ln1g, ln1b, h1, M_);
  gemm_k<0><<<dim3(24, 43), 256, 0, stream>>>(h1, wb, bqkv, nullptr, nullptr, qkvb, nullptr, 1024, 3072, M_);
  attn_k<<<dim3(11, 64), 256, 0, stream>>>(qkvb, ob);
  gemm_k<1><<<dim3(8, 43), 256, 0, stream>>>(ob, wb + 3145728, bproj, x, g1, nullptr, x2, 1024, 1024, M_);
  ln_k<<<MPAD, 256, 0, stream>>>(x2, ln2g, ln2b, h2, M_);
  gemm_k<2><<<dim3(32, 43), 256, 0, stream>>>(h2, wb + 4194304, bfc1, nullptr, nullptr, mlp, nullptr, 1024, 4096, M_);
  gemm_k<1><<<dim3(8, 43), 256, 0, stream>>>(mlp, wb + 8388608, bfc2, x2, g2, nullptr, out, 4096, 1024, M_);
}

// Round 3
// 388.961 us; speedup vs baseline: 1.2513x; 1.0480x over previous
//
#include <hip/hip_runtime.h>
#include <hip/hip_bf16.h>
#include <math.h>

#define B_ 4
#define N_ 1370
#define C_ 1024
#define H_ 16
#define DH_ 64
#define HID_ 4096
#define M_ (B_*N_)      // 5480
#define MPAD 5504       // 43*128

typedef short v8s __attribute__((ext_vector_type(8)));
typedef short v4s16 __attribute__((ext_vector_type(4)));
typedef float v4f __attribute__((ext_vector_type(4)));
typedef float v16f __attribute__((ext_vector_type(16)));

__device__ __forceinline__ short f2bf(float x) {
  union { float f; unsigned u; } a; a.f = x;
  unsigned r = (a.u + 0x7fffu + ((a.u >> 16) & 1u)) >> 16;
  return (short)r;
}

__device__ __forceinline__ void gl_lds16(const void* g, void* l) {
  __builtin_amdgcn_global_load_lds(
      (const __attribute__((address_space(1))) unsigned int*)g,
      (__attribute__((address_space(3))) unsigned int*)l, 16, 0, 0);
}

// ---- cast all four weight matrices f32 -> bf16 into one contiguous ws region
__global__ __launch_bounds__(256) void cast_w(const float* __restrict__ wq, const float* __restrict__ wp,
                                              const float* __restrict__ w1, const float* __restrict__ w2,
                                              short* __restrict__ out) {
  int i = blockIdx.x * 256 + threadIdx.x;
  int e = i << 2;
  const float* src; int off;
  if (e < 3145728)      { src = wq; off = e; }
  else if (e < 4194304) { src = wp; off = e - 3145728; }
  else if (e < 8388608) { src = w1; off = e - 4194304; }
  else                  { src = w2; off = e - 8388608; }
  float4 v = *reinterpret_cast<const float4*>(src + off);
  v4s16 o;
  o[0] = f2bf(v.x); o[1] = f2bf(v.y); o[2] = f2bf(v.z); o[3] = f2bf(v.w);
  *reinterpret_cast<v4s16*>(out + e) = o;
}

// ---- layernorm (f32 in, bf16 out), one block per row, pad rows -> zeros
__global__ __launch_bounds__(256) void ln_k(const float* __restrict__ x, const float* __restrict__ g,
                                            const float* __restrict__ bt, short* __restrict__ out, int mreal) {
  int row = blockIdx.x, t = threadIdx.x;
  short* orow = out + (size_t)row * C_;
  if (row >= mreal) {
    v4s16 z = {0,0,0,0};
    reinterpret_cast<v4s16*>(orow)[t] = z;
    return;
  }
  float4 v = reinterpret_cast<const float4*>(x + (size_t)row * C_)[t];
  float s = v.x + v.y + v.z + v.w;
  float q = v.x*v.x + v.y*v.y + v.z*v.z + v.w*v.w;
#pragma unroll
  for (int m = 1; m < 64; m <<= 1) { s += __shfl_xor(s, m); q += __shfl_xor(q, m); }
  __shared__ float sb[8];
  int w = t >> 6;
  if ((t & 63) == 0) { sb[w] = s; sb[4 + w] = q; }
  __syncthreads();
  s = sb[0] + sb[1] + sb[2] + sb[3];
  q = sb[4] + sb[5] + sb[6] + sb[7];
  float mean = s * (1.f / C_);
  float rstd = rsqrtf(q * (1.f / C_) - mean * mean + 1e-5f);
  float4 gv = reinterpret_cast<const float4*>(g)[t];
  float4 bv = reinterpret_cast<const float4*>(bt)[t];
  v4s16 o;
  o[0] = f2bf((v.x - mean) * rstd * gv.x + bv.x);
  o[1] = f2bf((v.y - mean) * rstd * gv.y + bv.y);
  o[2] = f2bf((v.z - mean) * rstd * gv.z + bv.z);
  o[3] = f2bf((v.w - mean) * rstd * gv.w + bv.w);
  reinterpret_cast<v4s16*>(orow)[t] = o;
}

// ---- 128x128-tile bf16 GEMM, 2-phase double-buffered (T3 minimum), one barrier/K-step
// C[r][c] = sum_k A[r][k]*Bw[c][k] (+ epilogue)
// MODE 0: obf = bf16( (v+bias) * (col<1024 ? 0.125*log2e : 1) )   [QKV]
// MODE 1: of32 = resid + gamma*(v+bias)   (rows < mreal)          [proj / fc2]
// MODE 2: obf = bf16( gelu_exact(v+bias) )                        [fc1]
template<int MODE>
__global__ __launch_bounds__(256) void gemm_k(
    const short* __restrict__ A, const short* __restrict__ Bw,
    const float* __restrict__ bias, const float* __restrict__ resid,
    const float* __restrict__ gamma, short* __restrict__ obf,
    float* __restrict__ of32, int K, int Nc, int mreal)
{
  __shared__ short As[2][128 * 32];
  __shared__ short Bs[2][128 * 32];
  int tid = threadIdx.x;
  int lane = tid & 63, wave = tid >> 6;
  int l15 = lane & 15, lhi = lane >> 4;
  int tn = blockIdx.x, tm = blockIdx.y;
  int wr = wave >> 1, wc = wave & 1;

  v4f acc[4][4];
#pragma unroll
  for (int m = 0; m < 4; m++)
#pragma unroll
    for (int n = 0; n < 4; n++) acc[m][n] = v4f{0.f, 0.f, 0.f, 0.f};

  int lrow = lane >> 2, lch = lane & 3;
  int scol = ((lch ^ ((lrow >> 1) & 3)) << 3);
  const short* Ag = A + (size_t)(tm * 128 + wave * 16 + lrow) * K + scol;
  const short* Bg = Bw + (size_t)(tn * 128 + wave * 16 + lrow) * K + scol;
  int fch = ((lhi ^ ((l15 >> 1) & 3)) << 3);

#define STAGE_G(bi, k0)                                               \
  do {                                                                \
    gl_lds16(Ag + (k0), &As[bi][wave * 512]);                         \
    gl_lds16(Ag + (size_t)64 * K + (k0), &As[bi][2048 + wave * 512]); \
    gl_lds16(Bg + (k0), &Bs[bi][wave * 512]);                         \
    gl_lds16(Bg + (size_t)64 * K + (k0), &Bs[bi][2048 + wave * 512]); \
  } while (0)

  int kT = K >> 5;
  STAGE_G(0, 0);
  __syncthreads();              // implicit vmcnt(0) drain before s_barrier
  int buf = 0;
  for (int kt = 0; kt < kT; ++kt) {
    if (kt + 1 < kT) STAGE_G(buf ^ 1, (kt + 1) << 5);   // prefetch in flight across MFMA phase
    v8s af[4], bfr[4];
#pragma unroll
    for (int m = 0; m < 4; m++)
      af[m] = *reinterpret_cast<const v8s*>(&As[buf][(wr * 64 + m * 16 + l15) * 32 + fch]);
#pragma unroll
    for (int n = 0; n < 4; n++)
      bfr[n] = *reinterpret_cast<const v8s*>(&Bs[buf][(wc * 64 + n * 16 + l15) * 32 + fch]);
#pragma unroll
    for (int m = 0; m < 4; m++)
#pragma unroll
      for (int n = 0; n < 4; n++)
        acc[m][n] = __builtin_amdgcn_mfma_f32_16x16x32_bf16(af[m], bfr[n], acc[m][n], 0, 0, 0);
    __syncthreads();            // drains prefetch vmcnt + releases buf^1 for next stage
    buf ^= 1;
  }
#undef STAGE_G

  int row0 = tm * 128 + wr * 64 + (lhi << 2);
  int col0 = tn * 128 + wc * 64 + l15;
#pragma unroll
  for (int m = 0; m < 4; m++) {
#pragma unroll
    for (int n = 0; n < 4; n++) {
      int gc = col0 + n * 16;
      float bb = bias[gc];
      float gm = (MODE == 1) ? gamma[gc] : 0.f;
#pragma unroll
      for (int r = 0; r < 4; r++) {
        int gr = row0 + m * 16 + r;
        float v = acc[m][n][r] + bb;
        if (MODE == 0) {
          float sc = (gc < 1024) ? 0.18033688011112042f : 1.0f;  // 0.125 * log2(e)
          obf[(size_t)gr * Nc + gc] = f2bf(v * sc);
        } else if (MODE == 2) {
          obf[(size_t)gr * Nc + gc] = f2bf(0.5f * v * (1.f + erff(v * 0.70710678f)));
        } else {
          if (gr < mreal) of32[(size_t)gr * Nc + gc] = resid[(size_t)gr * Nc + gc] + gm * v;
        }
      }
    }
  }
}

// ---- P fragment builder: 8 f32 (C/D-layout regs) -> A-frag via cvt_pk + permlane32_swap (T12)
__device__ __forceinline__ v8s pack_swap(const float* p) {
  unsigned w0, w1, w2, w3;
  asm("v_cvt_pk_bf16_f32 %0, %1, %2" : "=v"(w0) : "v"(p[0]), "v"(p[1]));
  asm("v_cvt_pk_bf16_f32 %0, %1, %2" : "=v"(w1) : "v"(p[2]), "v"(p[3]));
  asm("v_cvt_pk_bf16_f32 %0, %1, %2" : "=v"(w2) : "v"(p[4]), "v"(p[5]));
  asm("v_cvt_pk_bf16_f32 %0, %1, %2" : "=v"(w3) : "v"(p[6]), "v"(p[7]));
  asm("v_permlane32_swap_b32 %0, %1" : "+v"(w0), "+v"(w2));
  asm("v_permlane32_swap_b32 %0, %1" : "+v"(w1), "+v"(w3));
  union { unsigned u[4]; v8s s; } r;
  r.u[0] = w0; r.u[1] = w1; r.u[2] = w2; r.u[3] = w3;
  return r.s;
}

// ---- flash attention, swapped-QK^T 32x32x16 structure (m214 style)
// block: 4 waves x 32 q-rows = 128 q; KV tiles of 64. grid (ceil(N/128), B*H)
__global__ __launch_bounds__(256) void attn_k(const short* __restrict__ qkv, short* __restrict__ o)
{
  int qt = blockIdx.x, bh = blockIdx.y;
  int b = bh >> 4, h = bh & 15;
  int tid = threadIdx.x;
  int lane = tid & 63, wave = tid >> 6;
  int l31 = lane & 31, hi = lane >> 5;

  __shared__ short Ks[64 * 64];   // [kv][d], 16B-chunk ^= (kv&7), filled linearly by gl_lds w/ pre-swizzled src
  __shared__ short Vt[64 * 64];   // [d][kv], 8-elem chunk ^= ((d>>1)&7)

  int qrow = qt * 128 + wave * 32 + l31;
  int qc = qrow < N_ ? qrow : N_ - 1;
  const short* qp = qkv + (size_t)(b * N_ + qc) * 3072 + h * 64;
  v8s qf[4];
#pragma unroll
  for (int i = 0; i < 4; i++) qf[i] = *reinterpret_cast<const v8s*>(qp + i * 16 + hi * 8);

  v16f oa0, oa1;
#pragma unroll
  for (int r = 0; r < 16; r++) { oa0[r] = 0.f; oa1[r] = 0.f; }
  float m = -INFINITY, ls = 0.f;

  int kvA = wave * 8 + (lane >> 3);
  int kchunk = ((lane & 7) ^ (kvA & 7)) << 3;
  short* ldsKA = Ks + wave * 512;
  short* ldsKB = Ks + 2048 + wave * 512;

  int vkv = tid & 63, vd0 = (tid >> 6) << 4;

  const int NT = (N_ + 63) / 64;   // 22
  for (int t = 0; t < NT; ++t) {
    int kv0 = t * 64;
    int ra = kv0 + kvA;      ra = ra < N_ ? ra : N_ - 1;
    int rb = kv0 + kvA + 32; rb = rb < N_ ? rb : N_ - 1;
    int rv = kv0 + vkv;      rv = rv < N_ ? rv : N_ - 1;
    const short* vsrc = qkv + (size_t)(b * N_ + rv) * 3072 + 2048 + h * 64 + vd0;
    v8s va = *reinterpret_cast<const v8s*>(vsrc);
    v8s vb2 = *reinterpret_cast<const v8s*>(vsrc + 8);
    __syncthreads();
    gl_lds16(qkv + (size_t)(b * N_ + ra) * 3072 + 1024 + h * 64 + kchunk, ldsKA);
    gl_lds16(qkv + (size_t)(b * N_ + rb) * 3072 + 1024 + h * 64 + kchunk, ldsKB);
#pragma unroll
    for (int j = 0; j < 8; j++) {
      int d = vd0 + j;
      Vt[d * 64 + (((vkv >> 3) ^ ((d >> 1) & 7)) << 3) + (vkv & 7)] = va[j];
      int d2 = d + 8;
      Vt[d2 * 64 + (((vkv >> 3) ^ ((d2 >> 1) & 7)) << 3) + (vkv & 7)] = vb2[j];
    }
    __syncthreads();

    v16f s0, s1;
#pragma unroll
    for (int r = 0; r < 16; r++) { s0[r] = 0.f; s1[r] = 0.f; }
#pragma unroll
    for (int i = 0; i < 4; i++) {
      int c0 = ((2 * i + hi) ^ (l31 & 7)) << 3;
      v8s ka = *reinterpret_cast<const v8s*>(Ks + l31 * 64 + c0);
      v8s kb = *reinterpret_cast<const v8s*>(Ks + (32 + l31) * 64 + c0);
      s0 = __builtin_amdgcn_mfma_f32_32x32x16_bf16(ka, qf[i], s0, 0, 0, 0);
      s1 = __builtin_amdgcn_mfma_f32_32x32x16_bf16(kb, qf[i], s1, 0, 0, 0);
    }

    if (kv0 + 64 > N_) {
#pragma unroll
      for (int r = 0; r < 16; r++) {
        int crow = (r & 3) + 8 * (r >> 2) + 4 * hi;
        if (kv0 + crow >= N_) s0[r] = -1e30f;
        if (kv0 + 32 + crow >= N_) s1[r] = -1e30f;
      }
    }

    float pmax = s0[0];
#pragma unroll
    for (int r = 1; r < 16; r++) pmax = fmaxf(pmax, s0[r]);
#pragma unroll
    for (int r = 0; r < 16; r++) pmax = fmaxf(pmax, s1[r]);
    pmax = fmaxf(pmax, __shfl_xor(pmax, 32));

    if (!__all(pmax <= m + 11.0f)) {
      float mn = fmaxf(m, pmax);
      float scf = exp2f(m - mn);
      m = mn;
#pragma unroll
      for (int r = 0; r < 16; r++) {
        int crow = (r & 3) + 8 * (r >> 2) + 4 * hi;
        float sv = __shfl(scf, crow);
        oa0[r] *= sv; oa1[r] *= sv;
      }
      ls *= scf;
    }

    float p0[16], p1[16];
    float psum = 0.f;
#pragma unroll
    for (int r = 0; r < 16; r++) { p0[r] = exp2f(s0[r] - m); psum += p0[r]; }
#pragma unroll
    for (int r = 0; r < 16; r++) { p1[r] = exp2f(s1[r] - m); psum += p1[r]; }
    psum += __shfl_xor(psum, 32);
    ls += psum;

    v8s pa0 = pack_swap(p0), pa1 = pack_swap(p0 + 8), pa2 = pack_swap(p1), pa3 = pack_swap(p1 + 8);

#pragma unroll
    for (int i = 0; i < 4; i++) {
      v8s pai = (i == 0) ? pa0 : (i == 1) ? pa1 : (i == 2) ? pa2 : pa3;
      int cc = ((2 * i + hi) ^ ((l31 >> 1) & 7)) << 3;
      v8s v0f = *reinterpret_cast<const v8s*>(Vt + l31 * 64 + cc);
      v8s v1f = *reinterpret_cast<const v8s*>(Vt + (32 + l31) * 64 + cc);
      oa0 = __builtin_amdgcn_mfma_f32_32x32x16_bf16(pai, v0f, oa0, 0, 0, 0);
      oa1 = __builtin_amdgcn_mfma_f32_32x32x16_bf16(pai, v1f, oa1, 0, 0, 0);
    }
  }

  float inv = 1.f / ls;
#pragma unroll
  for (int r = 0; r < 16; r++) {
    int crow = (r & 3) + 8 * (r >> 2) + 4 * hi;
    float iv = __shfl(inv, crow);
    int qg = qt * 128 + wave * 32 + crow;
    if (qg < N_) {
      size_t base = (size_t)(b * N_ + qg) * 1024 + h * 64;
      o[base + l31] = f2bf(oa0[r] * iv);
      o[base + 32 + l31] = f2bf(oa1[r] * iv);
    }
  }
}

extern "C" void kernel_launch(void* const* d_in, const int* in_sizes, int n_in,
                              void* d_out, int out_size, void* d_ws, size_t ws_size,
                              hipStream_t stream) {
  const float* x     = (const float*)d_in[0];
  const float* ln1g  = (const float*)d_in[1];
  const float* ln1b  = (const float*)d_in[2];
  const float* wqkv  = (const float*)d_in[3];
  const float* bqkv  = (const float*)d_in[4];
  const float* wproj = (const float*)d_in[5];
  const float* bproj = (const float*)d_in[6];
  const float* g1    = (const float*)d_in[7];
  const float* ln2g  = (const float*)d_in[8];
  const float* ln2b  = (const float*)d_in[9];
  const float* wfc1  = (const float*)d_in[10];
  const float* bfc1  = (const float*)d_in[11];
  const float* wfc2  = (const float*)d_in[12];
  const float* bfc2  = (const float*)d_in[13];
  const float* g2    = (const float*)d_in[14];
  float* out = (float*)d_out;

  char* p = (char*)d_ws;
  short* wb   = (short*)(p);                 // bf16 weights, 25,165,824 B
  short* h1   = (short*)(p + 25165824);      // bf16 [MPAD][1024]
  short* qkvb = (short*)(p + 36438016);      // bf16 [MPAD][3072]
  short* ob   = (short*)(p + 70254592);      // bf16 [MPAD][1024]
  float* x2   = (float*)(p + 81526784);      // f32  [MPAD][1024]  (end 104,071,168)
  short* h2   = ob;                          // reuse (proj consumed ob before LN2)
  short* mlp  = h1;                          // reuse h1+qkvb region: [MPAD][4096] bf16

  cast_w<<<12288, 256, 0, stream>>>(wqkv, wproj, wfc1, wfc2, wb);
  ln_k<<<MPAD, 256, 0, stream>>>(x, ln1g, ln1b, h1, M_);
  gemm_k<0><<<dim3(24, 43), 256, 0, stream>>>(h1, wb, bqkv, nullptr, nullptr, qkvb, nullptr, 1024, 3072, M_);
  attn_k<<<dim3(11, 64), 256, 0, stream>>>(qkvb, ob);
  gemm_k<1><<<dim3(8, 43), 256, 0, stream>>>(ob, wb + 3145728, bproj, x, g1, nullptr, x2, 1024, 1024, M_);
  ln_k<<<MPAD, 256, 0, stream>>>(x2, ln2g, ln2b, h2, M_);
  gemm_k<2><<<dim3(32, 43), 256, 0, stream>>>(h2, wb + 4194304, bfc1, nullptr, nullptr, mlp, nullptr, 1024, 4096, M_);
  gemm_k<1><<<dim3(8, 43), 256, 0, stream>>>(mlp, wb + 8388608, bfc2, x2, g2, nullptr, out, 4096, 1024, M_);
}

// Round 4
// 368.283 us; speedup vs baseline: 1.3216x; 1.0561x over previous
//
#include <hip/hip_runtime.h>
#include <hip/hip_bf16.h>
#include <math.h>

#define B_ 4
#define N_ 1370
#define C_ 1024
#define H_ 16
#define DH_ 64
#define HID_ 4096
#define M_ (B_*N_)      // 5480
#define MPAD 5504       // 43*128

typedef short v8s __attribute__((ext_vector_type(8)));
typedef short v4s16 __attribute__((ext_vector_type(4)));
typedef float v4f __attribute__((ext_vector_type(4)));
typedef float v16f __attribute__((ext_vector_type(16)));

__device__ __forceinline__ short f2bf(float x) {
  union { float f; unsigned u; } a; a.f = x;
  unsigned r = (a.u + 0x7fffu + ((a.u >> 16) & 1u)) >> 16;
  return (short)r;
}

__device__ __forceinline__ void gl_lds16(const void* g, void* l) {
  __builtin_amdgcn_global_load_lds(
      (const __attribute__((address_space(1))) unsigned int*)g,
      (__attribute__((address_space(3))) unsigned int*)l, 16, 0, 0);
}

// ---- cast all four weight matrices f32 -> bf16 into one contiguous ws region
__global__ __launch_bounds__(256) void cast_w(const float* __restrict__ wq, const float* __restrict__ wp,
                                              const float* __restrict__ w1, const float* __restrict__ w2,
                                              short* __restrict__ out) {
  int i = blockIdx.x * 256 + threadIdx.x;
  int e = i << 2;
  const float* src; int off;
  if (e < 3145728)      { src = wq; off = e; }
  else if (e < 4194304) { src = wp; off = e - 3145728; }
  else if (e < 8388608) { src = w1; off = e - 4194304; }
  else                  { src = w2; off = e - 8388608; }
  float4 v = *reinterpret_cast<const float4*>(src + off);
  v4s16 o;
  o[0] = f2bf(v.x); o[1] = f2bf(v.y); o[2] = f2bf(v.z); o[3] = f2bf(v.w);
  *reinterpret_cast<v4s16*>(out + e) = o;
}

// ---- layernorm (f32 in, bf16 out), one block per row, pad rows -> zeros
__global__ __launch_bounds__(256) void ln_k(const float* __restrict__ x, const float* __restrict__ g,
                                            const float* __restrict__ bt, short* __restrict__ out, int mreal) {
  int row = blockIdx.x, t = threadIdx.x;
  short* orow = out + (size_t)row * C_;
  if (row >= mreal) {
    v4s16 z = {0,0,0,0};
    reinterpret_cast<v4s16*>(orow)[t] = z;
    return;
  }
  float4 v = reinterpret_cast<const float4*>(x + (size_t)row * C_)[t];
  float s = v.x + v.y + v.z + v.w;
  float q = v.x*v.x + v.y*v.y + v.z*v.z + v.w*v.w;
#pragma unroll
  for (int m = 1; m < 64; m <<= 1) { s += __shfl_xor(s, m); q += __shfl_xor(q, m); }
  __shared__ float sb[8];
  int w = t >> 6;
  if ((t & 63) == 0) { sb[w] = s; sb[4 + w] = q; }
  __syncthreads();
  s = sb[0] + sb[1] + sb[2] + sb[3];
  q = sb[4] + sb[5] + sb[6] + sb[7];
  float mean = s * (1.f / C_);
  float rstd = rsqrtf(q * (1.f / C_) - mean * mean + 1e-5f);
  float4 gv = reinterpret_cast<const float4*>(g)[t];
  float4 bv = reinterpret_cast<const float4*>(bt)[t];
  v4s16 o;
  o[0] = f2bf((v.x - mean) * rstd * gv.x + bv.x);
  o[1] = f2bf((v.y - mean) * rstd * gv.y + bv.y);
  o[2] = f2bf((v.z - mean) * rstd * gv.z + bv.z);
  o[3] = f2bf((v.w - mean) * rstd * gv.w + bv.w);
  reinterpret_cast<v4s16*>(orow)[t] = o;
}

// ---- 128x128-tile bf16 GEMM, 3-buffer counted-vmcnt pipeline (T3+T4+T5)
// C[r][c] = sum_k A[r][k]*Bw[c][k] (+ epilogue)
// MODE 0: obf = bf16( (v+bias) * (col<1024 ? 0.125*log2e : 1) )   [QKV]
// MODE 1: of32 = resid + gamma*(v+bias)   (rows < mreal)          [proj / fc2]
// MODE 2: obf = bf16( gelu_exact(v+bias) )                        [fc1]
template<int MODE>
__global__ __launch_bounds__(256) void gemm_k(
    const short* __restrict__ A, const short* __restrict__ Bw,
    const float* __restrict__ bias, const float* __restrict__ resid,
    const float* __restrict__ gamma, short* __restrict__ obf,
    float* __restrict__ of32, int K, int Nc, int mreal)
{
  __shared__ short As[3][128 * 32];
  __shared__ short Bs[3][128 * 32];
  int tid = threadIdx.x;
  int lane = tid & 63, wave = tid >> 6;
  int l15 = lane & 15, lhi = lane >> 4;
  int tn = blockIdx.x, tm = blockIdx.y;
  int wr = wave >> 1, wc = wave & 1;

  v4f acc[4][4];
#pragma unroll
  for (int m = 0; m < 4; m++)
#pragma unroll
    for (int n = 0; n < 4; n++) acc[m][n] = v4f{0.f, 0.f, 0.f, 0.f};

  int lrow = lane >> 2, lch = lane & 3;
  int scol = ((lch ^ ((lrow >> 1) & 3)) << 3);
  const short* Ag = A + (size_t)(tm * 128 + wave * 16 + lrow) * K + scol;
  const short* Bg = Bw + (size_t)(tn * 128 + wave * 16 + lrow) * K + scol;
  int fch = ((lhi ^ ((l15 >> 1) & 3)) << 3);

#define STAGE_G(bi, k0)                                                   \
  do {                                                                    \
    gl_lds16(Ag + (k0), &As[bi][wave * 512]);                             \
    gl_lds16(Ag + (size_t)64 * K + (k0), &As[bi][2048 + wave * 512]);     \
    gl_lds16(Bg + (k0), &Bs[bi][wave * 512]);                             \
    gl_lds16(Bg + (size_t)64 * K + (k0), &Bs[bi][2048 + wave * 512]);     \
  } while (0)

  int kT = K >> 5;   // 32 or 128, always >= 3

  // prologue: stages 0,1,2 in flight
  STAGE_G(0, 0);
  STAGE_G(1, 1 << 5);
  STAGE_G(2, 2 << 5);

  auto body = [&](int t, int bb, bool stage_next) {
    __builtin_amdgcn_s_barrier();             // all waves' stage-t loads landed
    v8s af[4], bfr[4];
#pragma unroll
    for (int m = 0; m < 4; m++)
      af[m] = *reinterpret_cast<const v8s*>(&As[bb][(wr * 64 + m * 16 + l15) * 32 + fch]);
#pragma unroll
    for (int n = 0; n < 4; n++)
      bfr[n] = *reinterpret_cast<const v8s*>(&Bs[bb][(wc * 64 + n * 16 + l15) * 32 + fch]);
    asm volatile("s_waitcnt lgkmcnt(0)" ::: "memory");   // my reads actually returned
    __builtin_amdgcn_s_barrier();             // everyone done reading buf bb
    if (stage_next) STAGE_G(bb, (t + 3) << 5);            // overwrite bb; lands by iter t+3
    __builtin_amdgcn_s_setprio(1);
#pragma unroll
    for (int m = 0; m < 4; m++)
#pragma unroll
      for (int n = 0; n < 4; n++)
        acc[m][n] = __builtin_amdgcn_mfma_f32_16x16x32_bf16(af[m], bfr[n], acc[m][n], 0, 0, 0);
    __builtin_amdgcn_s_setprio(0);
  };

  int b = 0, t = 0;
  for (; t < kT - 2; ++t) {
    asm volatile("s_waitcnt vmcnt(8)" ::: "memory");   // stages t+1,t+2 (8 loads) newer -> stage t done
    body(t, b, t + 3 < kT);
    b = (b == 2) ? 0 : b + 1;
  }
  asm volatile("s_waitcnt vmcnt(4)" ::: "memory");     // only stage kT-1 newer
  body(kT - 2, b, false);
  b = (b == 2) ? 0 : b + 1;
  asm volatile("s_waitcnt vmcnt(0)" ::: "memory");
  body(kT - 1, b, false);
#undef STAGE_G

  int row0 = tm * 128 + wr * 64 + (lhi << 2);
  int col0 = tn * 128 + wc * 64 + l15;
#pragma unroll
  for (int m = 0; m < 4; m++) {
#pragma unroll
    for (int n = 0; n < 4; n++) {
      int gc = col0 + n * 16;
      float bb = bias[gc];
      float gm = (MODE == 1) ? gamma[gc] : 0.f;
#pragma unroll
      for (int r = 0; r < 4; r++) {
        int gr = row0 + m * 16 + r;
        float v = acc[m][n][r] + bb;
        if (MODE == 0) {
          float sc = (gc < 1024) ? 0.18033688011112042f : 1.0f;  // 0.125 * log2(e)
          obf[(size_t)gr * Nc + gc] = f2bf(v * sc);
        } else if (MODE == 2) {
          obf[(size_t)gr * Nc + gc] = f2bf(0.5f * v * (1.f + erff(v * 0.70710678f)));
        } else {
          if (gr < mreal) of32[(size_t)gr * Nc + gc] = resid[(size_t)gr * Nc + gc] + gm * v;
        }
      }
    }
  }
}

// ---- P fragment builder: 8 f32 (C/D-layout regs) -> A-frag via cvt_pk + permlane32_swap (T12)
__device__ __forceinline__ v8s pack_swap(const float* p) {
  unsigned w0, w1, w2, w3;
  asm("v_cvt_pk_bf16_f32 %0, %1, %2" : "=v"(w0) : "v"(p[0]), "v"(p[1]));
  asm("v_cvt_pk_bf16_f32 %0, %1, %2" : "=v"(w1) : "v"(p[2]), "v"(p[3]));
  asm("v_cvt_pk_bf16_f32 %0, %1, %2" : "=v"(w2) : "v"(p[4]), "v"(p[5]));
  asm("v_cvt_pk_bf16_f32 %0, %1, %2" : "=v"(w3) : "v"(p[6]), "v"(p[7]));
  asm("v_permlane32_swap_b32 %0, %1" : "+v"(w0), "+v"(w2));
  asm("v_permlane32_swap_b32 %0, %1" : "+v"(w1), "+v"(w3));
  union { unsigned u[4]; v8s s; } r;
  r.u[0] = w0; r.u[1] = w1; r.u[2] = w2; r.u[3] = w3;
  return r.s;
}

// ---- flash attention, swapped-QK^T 32x32x16 structure (m214 style)
// block: 4 waves x 32 q-rows = 128 q; KV tiles of 64. grid (ceil(N/128), B*H)
__global__ __launch_bounds__(256) void attn_k(const short* __restrict__ qkv, short* __restrict__ o)
{
  int qt = blockIdx.x, bh = blockIdx.y;
  int b = bh >> 4, h = bh & 15;
  int tid = threadIdx.x;
  int lane = tid & 63, wave = tid >> 6;
  int l31 = lane & 31, hi = lane >> 5;

  __shared__ short Ks[64 * 64];   // [kv][d], 16B-chunk ^= (kv&7), filled linearly by gl_lds w/ pre-swizzled src
  __shared__ short Vt[64 * 64];   // [d][kv], 8-elem chunk ^= ((d>>1)&7)

  int qrow = qt * 128 + wave * 32 + l31;
  int qc = qrow < N_ ? qrow : N_ - 1;
  const short* qp = qkv + (size_t)(b * N_ + qc) * 3072 + h * 64;
  v8s qf[4];
#pragma unroll
  for (int i = 0; i < 4; i++) qf[i] = *reinterpret_cast<const v8s*>(qp + i * 16 + hi * 8);

  v16f oa0, oa1;
#pragma unroll
  for (int r = 0; r < 16; r++) { oa0[r] = 0.f; oa1[r] = 0.f; }
  float m = -INFINITY, ls = 0.f;

  int kvA = wave * 8 + (lane >> 3);
  int kchunk = ((lane & 7) ^ (kvA & 7)) << 3;
  short* ldsKA = Ks + wave * 512;
  short* ldsKB = Ks + 2048 + wave * 512;

  int vkv = tid & 63, vd0 = (tid >> 6) << 4;

  const int NT = (N_ + 63) / 64;   // 22
  for (int t = 0; t < NT; ++t) {
    int kv0 = t * 64;
    int ra = kv0 + kvA;      ra = ra < N_ ? ra : N_ - 1;
    int rb = kv0 + kvA + 32; rb = rb < N_ ? rb : N_ - 1;
    int rv = kv0 + vkv;      rv = rv < N_ ? rv : N_ - 1;
    const short* vsrc = qkv + (size_t)(b * N_ + rv) * 3072 + 2048 + h * 64 + vd0;
    v8s va = *reinterpret_cast<const v8s*>(vsrc);
    v8s vb2 = *reinterpret_cast<const v8s*>(vsrc + 8);
    __syncthreads();
    gl_lds16(qkv + (size_t)(b * N_ + ra) * 3072 + 1024 + h * 64 + kchunk, ldsKA);
    gl_lds16(qkv + (size_t)(b * N_ + rb) * 3072 + 1024 + h * 64 + kchunk, ldsKB);
#pragma unroll
    for (int j = 0; j < 8; j++) {
      int d = vd0 + j;
      Vt[d * 64 + (((vkv >> 3) ^ ((d >> 1) & 7)) << 3) + (vkv & 7)] = va[j];
      int d2 = d + 8;
      Vt[d2 * 64 + (((vkv >> 3) ^ ((d2 >> 1) & 7)) << 3) + (vkv & 7)] = vb2[j];
    }
    __syncthreads();

    v16f s0, s1;
#pragma unroll
    for (int r = 0; r < 16; r++) { s0[r] = 0.f; s1[r] = 0.f; }
#pragma unroll
    for (int i = 0; i < 4; i++) {
      int c0 = ((2 * i + hi) ^ (l31 & 7)) << 3;
      v8s ka = *reinterpret_cast<const v8s*>(Ks + l31 * 64 + c0);
      v8s kb = *reinterpret_cast<const v8s*>(Ks + (32 + l31) * 64 + c0);
      s0 = __builtin_amdgcn_mfma_f32_32x32x16_bf16(ka, qf[i], s0, 0, 0, 0);
      s1 = __builtin_amdgcn_mfma_f32_32x32x16_bf16(kb, qf[i], s1, 0, 0, 0);
    }

    if (kv0 + 64 > N_) {
#pragma unroll
      for (int r = 0; r < 16; r++) {
        int crow = (r & 3) + 8 * (r >> 2) + 4 * hi;
        if (kv0 + crow >= N_) s0[r] = -1e30f;
        if (kv0 + 32 + crow >= N_) s1[r] = -1e30f;
      }
    }

    float pmax = s0[0];
#pragma unroll
    for (int r = 1; r < 16; r++) pmax = fmaxf(pmax, s0[r]);
#pragma unroll
    for (int r = 0; r < 16; r++) pmax = fmaxf(pmax, s1[r]);
    pmax = fmaxf(pmax, __shfl_xor(pmax, 32));

    if (!__all(pmax <= m + 11.0f)) {
      float mn = fmaxf(m, pmax);
      float scf = exp2f(m - mn);
      m = mn;
#pragma unroll
      for (int r = 0; r < 16; r++) {
        int crow = (r & 3) + 8 * (r >> 2) + 4 * hi;
        float sv = __shfl(scf, crow);
        oa0[r] *= sv; oa1[r] *= sv;
      }
      ls *= scf;
    }

    float p0[16], p1[16];
    float psum = 0.f;
#pragma unroll
    for (int r = 0; r < 16; r++) { p0[r] = exp2f(s0[r] - m); psum += p0[r]; }
#pragma unroll
    for (int r = 0; r < 16; r++) { p1[r] = exp2f(s1[r] - m); psum += p1[r]; }
    psum += __shfl_xor(psum, 32);
    ls += psum;

    v8s pa0 = pack_swap(p0), pa1 = pack_swap(p0 + 8), pa2 = pack_swap(p1), pa3 = pack_swap(p1 + 8);

#pragma unroll
    for (int i = 0; i < 4; i++) {
      v8s pai = (i == 0) ? pa0 : (i == 1) ? pa1 : (i == 2) ? pa2 : pa3;
      int cc = ((2 * i + hi) ^ ((l31 >> 1) & 7)) << 3;
      v8s v0f = *reinterpret_cast<const v8s*>(Vt + l31 * 64 + cc);
      v8s v1f = *reinterpret_cast<const v8s*>(Vt + (32 + l31) * 64 + cc);
      oa0 = __builtin_amdgcn_mfma_f32_32x32x16_bf16(pai, v0f, oa0, 0, 0, 0);
      oa1 = __builtin_amdgcn_mfma_f32_32x32x16_bf16(pai, v1f, oa1, 0, 0, 0);
    }
  }

  float inv = 1.f / ls;
#pragma unroll
  for (int r = 0; r < 16; r++) {
    int crow = (r & 3) + 8 * (r >> 2) + 4 * hi;
    float iv = __shfl(inv, crow);
    int qg = qt * 128 + wave * 32 + crow;
    if (qg < N_) {
      size_t base = (size_t)(b * N_ + qg) * 1024 + h * 64;
      o[base + l31] = f2bf(oa0[r] * iv);
      o[base + 32 + l31] = f2bf(oa1[r] * iv);
    }
  }
}

extern "C" void kernel_launch(void* const* d_in, const int* in_sizes, int n_in,
                              void* d_out, int out_size, void* d_ws, size_t ws_size,
                              hipStream_t stream) {
  const float* x     = (const float*)d_in[0];
  const float* ln1g  = (const float*)d_in[1];
  const float* ln1b  = (const float*)d_in[2];
  const float* wqkv  = (const float*)d_in[3];
  const float* bqkv  = (const float*)d_in[4];
  const float* wproj = (const float*)d_in[5];
  const float* bproj = (const float*)d_in[6];
  const float* g1    = (const float*)d_in[7];
  const float* ln2g  = (const float*)d_in[8];
  const float* ln2b  = (const float*)d_in[9];
  const float* wfc1  = (const float*)d_in[10];
  const float* bfc1  = (const float*)d_in[11];
  const float* wfc2  = (const float*)d_in[12];
  const float* bfc2  = (const float*)d_in[13];
  const float* g2    = (const float*)d_in[14];
  float* out = (float*)d_out;

  char* p = (char*)d_ws;
  short* wb   = (short*)(p);                 // bf16 weights, 25,165,824 B
  short* h1   = (short*)(p + 25165824);      // bf16 [MPAD][1024]
  short* qkvb = (short*)(p + 36438016);      // bf16 [MPAD][3072]
  short* ob   = (short*)(p + 70254592);      // bf16 [MPAD][1024]
  float* x2   = (float*)(p + 81526784);      // f32  [MPAD][1024]  (end 104,071,168)
  short* h2   = ob;                          // reuse (proj consumed ob before LN2)
  short* mlp  = h1;                          // reuse h1+qkvb region: [MPAD][4096] bf16

  cast_w<<<12288, 256, 0, stream>>>(wqkv, wproj, wfc1, wfc2, wb);
  ln_k<<<MPAD, 256, 0, stream>>>(x, ln1g, ln1b, h1, M_);
  gemm_k<0><<<dim3(24, 43), 256, 0, stream>>>(h1, wb, bqkv, nullptr, nullptr, qkvb, nullptr, 1024, 3072, M_);
  attn_k<<<dim3(11, 64), 256, 0, stream>>>(qkvb, ob);
  gemm_k<1><<<dim3(8, 43), 256, 0, stream>>>(ob, wb + 3145728, bproj, x, g1, nullptr, x2, 1024, 1024, M_);
  ln_k<<<MPAD, 256, 0, stream>>>(x2, ln2g, ln2b, h2, M_);
  gemm_k<2><<<dim3(32, 43), 256, 0, stream>>>(h2, wb + 4194304, bfc1, nullptr, nullptr, mlp, nullptr, 1024, 4096, M_);
  gemm_k<1><<<dim3(8, 43), 256, 0, stream>>>(mlp, wb + 8388608, bfc2, x2, g2, nullptr, out, 4096, 1024, M_);
}

// Round 5
// 360.595 us; speedup vs baseline: 1.3497x; 1.0213x over previous
//
#include <hip/hip_runtime.h>
#include <hip/hip_bf16.h>
#include <math.h>

#define B_ 4
#define N_ 1370
#define C_ 1024
#define H_ 16
#define DH_ 64
#define HID_ 4096
#define M_ (B_*N_)      // 5480
#define MPAD 5504       // 43*128
#define NKV 1408        // 22*64 padded kv

typedef short v8s __attribute__((ext_vector_type(8)));
typedef short v4s16 __attribute__((ext_vector_type(4)));
typedef float v4f __attribute__((ext_vector_type(4)));
typedef float v16f __attribute__((ext_vector_type(16)));

__device__ __forceinline__ short f2bf(float x) {
  union { float f; unsigned u; } a; a.f = x;
  unsigned r = (a.u + 0x7fffu + ((a.u >> 16) & 1u)) >> 16;
  return (short)r;
}

__device__ __forceinline__ void gl_lds16(const void* g, void* l) {
  __builtin_amdgcn_global_load_lds(
      (const __attribute__((address_space(1))) unsigned int*)g,
      (__attribute__((address_space(3))) unsigned int*)l, 16, 0, 0);
}

// ---- cast all four weight matrices f32 -> bf16 into one contiguous ws region
__global__ __launch_bounds__(256) void cast_w(const float* __restrict__ wq, const float* __restrict__ wp,
                                              const float* __restrict__ w1, const float* __restrict__ w2,
                                              short* __restrict__ out) {
  int i = blockIdx.x * 256 + threadIdx.x;
  int e = i << 2;
  const float* src; int off;
  if (e < 3145728)      { src = wq; off = e; }
  else if (e < 4194304) { src = wp; off = e - 3145728; }
  else if (e < 8388608) { src = w1; off = e - 4194304; }
  else                  { src = w2; off = e - 8388608; }
  float4 v = *reinterpret_cast<const float4*>(src + off);
  v4s16 o;
  o[0] = f2bf(v.x); o[1] = f2bf(v.y); o[2] = f2bf(v.z); o[3] = f2bf(v.w);
  *reinterpret_cast<v4s16*>(out + e) = o;
}

// ---- layernorm (f32 in, bf16 out), one block per row, pad rows -> zeros
__global__ __launch_bounds__(256) void ln_k(const float* __restrict__ x, const float* __restrict__ g,
                                            const float* __restrict__ bt, short* __restrict__ out, int mreal) {
  int row = blockIdx.x, t = threadIdx.x;
  short* orow = out + (size_t)row * C_;
  if (row >= mreal) {
    v4s16 z = {0,0,0,0};
    reinterpret_cast<v4s16*>(orow)[t] = z;
    return;
  }
  float4 v = reinterpret_cast<const float4*>(x + (size_t)row * C_)[t];
  float s = v.x + v.y + v.z + v.w;
  float q = v.x*v.x + v.y*v.y + v.z*v.z + v.w*v.w;
#pragma unroll
  for (int m = 1; m < 64; m <<= 1) { s += __shfl_xor(s, m); q += __shfl_xor(q, m); }
  __shared__ float sb[8];
  int w = t >> 6;
  if ((t & 63) == 0) { sb[w] = s; sb[4 + w] = q; }
  __syncthreads();
  s = sb[0] + sb[1] + sb[2] + sb[3];
  q = sb[4] + sb[5] + sb[6] + sb[7];
  float mean = s * (1.f / C_);
  float rstd = rsqrtf(q * (1.f / C_) - mean * mean + 1e-5f);
  float4 gv = reinterpret_cast<const float4*>(g)[t];
  float4 bv = reinterpret_cast<const float4*>(bt)[t];
  v4s16 o;
  o[0] = f2bf((v.x - mean) * rstd * gv.x + bv.x);
  o[1] = f2bf((v.y - mean) * rstd * gv.y + bv.y);
  o[2] = f2bf((v.z - mean) * rstd * gv.z + bv.z);
  o[3] = f2bf((v.w - mean) * rstd * gv.w + bv.w);
  reinterpret_cast<v4s16*>(orow)[t] = o;
}

// ---- 128x128-tile bf16 GEMM, 3-buffer counted-vmcnt pipeline (T3+T4+T5)
// MODE 0: obf = bf16( (v+bias) * (col<1024 ? 0.125*log2e : 1) )   [QKV]
// MODE 1: of32 = resid + gamma*(v+bias)   (rows < mreal)          [proj / fc2]
// MODE 2: obf = bf16( gelu_exact(v+bias) )                        [fc1]
template<int MODE>
__global__ __launch_bounds__(256) void gemm_k(
    const short* __restrict__ A, const short* __restrict__ Bw,
    const float* __restrict__ bias, const float* __restrict__ resid,
    const float* __restrict__ gamma, short* __restrict__ obf,
    float* __restrict__ of32, int K, int Nc, int mreal)
{
  __shared__ short As[3][128 * 32];
  __shared__ short Bs[3][128 * 32];
  int tid = threadIdx.x;
  int lane = tid & 63, wave = tid >> 6;
  int l15 = lane & 15, lhi = lane >> 4;
  int tn = blockIdx.x, tm = blockIdx.y;
  int wr = wave >> 1, wc = wave & 1;

  v4f acc[4][4];
#pragma unroll
  for (int m = 0; m < 4; m++)
#pragma unroll
    for (int n = 0; n < 4; n++) acc[m][n] = v4f{0.f, 0.f, 0.f, 0.f};

  int lrow = lane >> 2, lch = lane & 3;
  int scol = ((lch ^ ((lrow >> 1) & 3)) << 3);
  const short* Ag = A + (size_t)(tm * 128 + wave * 16 + lrow) * K + scol;
  const short* Bg = Bw + (size_t)(tn * 128 + wave * 16 + lrow) * K + scol;
  int fch = ((lhi ^ ((l15 >> 1) & 3)) << 3);

#define STAGE_G(bi, k0)                                                   \
  do {                                                                    \
    gl_lds16(Ag + (k0), &As[bi][wave * 512]);                             \
    gl_lds16(Ag + (size_t)64 * K + (k0), &As[bi][2048 + wave * 512]);     \
    gl_lds16(Bg + (k0), &Bs[bi][wave * 512]);                             \
    gl_lds16(Bg + (size_t)64 * K + (k0), &Bs[bi][2048 + wave * 512]);     \
  } while (0)

  int kT = K >> 5;   // 32 or 128, always >= 3

  STAGE_G(0, 0);
  STAGE_G(1, 1 << 5);
  STAGE_G(2, 2 << 5);

  auto body = [&](int t, int bb, bool stage_next) {
    __builtin_amdgcn_s_barrier();
    v8s af[4], bfr[4];
#pragma unroll
    for (int m = 0; m < 4; m++)
      af[m] = *reinterpret_cast<const v8s*>(&As[bb][(wr * 64 + m * 16 + l15) * 32 + fch]);
#pragma unroll
    for (int n = 0; n < 4; n++)
      bfr[n] = *reinterpret_cast<const v8s*>(&Bs[bb][(wc * 64 + n * 16 + l15) * 32 + fch]);
    asm volatile("s_waitcnt lgkmcnt(0)" ::: "memory");
    __builtin_amdgcn_s_barrier();
    if (stage_next) STAGE_G(bb, (t + 3) << 5);
    __builtin_amdgcn_s_setprio(1);
#pragma unroll
    for (int m = 0; m < 4; m++)
#pragma unroll
      for (int n = 0; n < 4; n++)
        acc[m][n] = __builtin_amdgcn_mfma_f32_16x16x32_bf16(af[m], bfr[n], acc[m][n], 0, 0, 0);
    __builtin_amdgcn_s_setprio(0);
  };

  int b = 0, t = 0;
  for (; t < kT - 2; ++t) {
    asm volatile("s_waitcnt vmcnt(8)" ::: "memory");
    body(t, b, t + 3 < kT);
    b = (b == 2) ? 0 : b + 1;
  }
  asm volatile("s_waitcnt vmcnt(4)" ::: "memory");
  body(kT - 2, b, false);
  b = (b == 2) ? 0 : b + 1;
  asm volatile("s_waitcnt vmcnt(0)" ::: "memory");
  body(kT - 1, b, false);
#undef STAGE_G

  int row0 = tm * 128 + wr * 64 + (lhi << 2);
  int col0 = tn * 128 + wc * 64 + l15;
#pragma unroll
  for (int m = 0; m < 4; m++) {
#pragma unroll
    for (int n = 0; n < 4; n++) {
      int gc = col0 + n * 16;
      float bb = bias[gc];
      float gm = (MODE == 1) ? gamma[gc] : 0.f;
#pragma unroll
      for (int r = 0; r < 4; r++) {
        int gr = row0 + m * 16 + r;
        float v = acc[m][n][r] + bb;
        if (MODE == 0) {
          float sc = (gc < 1024) ? 0.18033688011112042f : 1.0f;  // 0.125 * log2(e)
          obf[(size_t)gr * Nc + gc] = f2bf(v * sc);
        } else if (MODE == 2) {
          obf[(size_t)gr * Nc + gc] = f2bf(0.5f * v * (1.f + erff(v * 0.70710678f)));
        } else {
          if (gr < mreal) of32[(size_t)gr * Nc + gc] = resid[(size_t)gr * Nc + gc] + gm * v;
        }
      }
    }
  }
}

// ---- V transpose: qkvb V-third [token][2048+h*64+d] -> vtg[(bh*64+d)][kv], kv padded to NKV
__global__ __launch_bounds__(256) void vtrans_k(const short* __restrict__ qkv, short* __restrict__ vt) {
  int kt = blockIdx.x;          // 0..10, 128 kv rows each
  int bh = blockIdx.y;          // 0..63
  int b = bh >> 4, h = bh & 15;
  int t = threadIdx.x;
  __shared__ short T[128][76];
  int n0 = kt * 128;
  // load 128 tokens x 64 d (clamped; pad rows multiplied by P=0 downstream)
  int r = t >> 1;
  int c0 = (t & 1) * 32;
  int tok = n0 + r;
  int tokc = tok < N_ ? tok : N_ - 1;
  const short* src = qkv + (size_t)(b * N_ + tokc) * 3072 + 2048 + h * 64 + c0;
  v8s a0 = *reinterpret_cast<const v8s*>(src);
  v8s a1 = *reinterpret_cast<const v8s*>(src + 8);
  v8s a2 = *reinterpret_cast<const v8s*>(src + 16);
  v8s a3 = *reinterpret_cast<const v8s*>(src + 24);
  *reinterpret_cast<v8s*>(&T[r][c0]) = a0;
  *reinterpret_cast<v8s*>(&T[r][c0 + 8]) = a1;
  *reinterpret_cast<v8s*>(&T[r][c0 + 16]) = a2;
  *reinterpret_cast<v8s*>(&T[r][c0 + 24]) = a3;
  __syncthreads();
  // write 64 d-rows x 128 kv; lane d = t&63 spreads banks (2-way), 64 B contiguous per thread
  int d = t & 63;
  int k0 = (t >> 6) * 32;
  short tmp[32];
#pragma unroll
  for (int j = 0; j < 32; j++) tmp[j] = T[k0 + j][d];
  short* dst = vt + ((size_t)bh * 64 + d) * NKV + n0 + k0;
#pragma unroll
  for (int j = 0; j < 32; j += 8)
    *reinterpret_cast<v8s*>(dst + j) = *reinterpret_cast<const v8s*>(&tmp[j]);
}

// ---- P fragment builder: 8 f32 (C/D-layout regs) -> A-frag via cvt_pk + permlane32_swap (T12)
__device__ __forceinline__ v8s pack_swap(const float* p) {
  unsigned w0, w1, w2, w3;
  asm("v_cvt_pk_bf16_f32 %0, %1, %2" : "=v"(w0) : "v"(p[0]), "v"(p[1]));
  asm("v_cvt_pk_bf16_f32 %0, %1, %2" : "=v"(w1) : "v"(p[2]), "v"(p[3]));
  asm("v_cvt_pk_bf16_f32 %0, %1, %2" : "=v"(w2) : "v"(p[4]), "v"(p[5]));
  asm("v_cvt_pk_bf16_f32 %0, %1, %2" : "=v"(w3) : "v"(p[6]), "v"(p[7]));
  asm("v_permlane32_swap_b32 %0, %1" : "+v"(w0), "+v"(w2));
  asm("v_permlane32_swap_b32 %0, %1" : "+v"(w1), "+v"(w3));
  union { unsigned u[4]; v8s s; } r;
  r.u[0] = w0; r.u[1] = w1; r.u[2] = w2; r.u[3] = w3;
  return r.s;
}

// ---- flash attention, swapped-QK^T 32x32x16, K+V gl_lds double-buffer, 1 barrier/tile
// block: 4 waves x 32 q-rows = 128 q; KV tiles of 64. grid (11, 64), XCD-swizzled
__global__ __launch_bounds__(256) void attn_k(const short* __restrict__ qkv, const short* __restrict__ vt,
                                              short* __restrict__ o)
{
  // XCD swizzle (T1): 704 blocks = 8 XCD x 88; same-bh blocks land on one XCD
  int s = blockIdx.x + 11 * blockIdx.y;
  int ord = (s & 7) * 88 + (s >> 3);
  int qt = ord % 11, bh = ord / 11;
  int b = bh >> 4, h = bh & 15;
  int tid = threadIdx.x;
  int lane = tid & 63, wave = tid >> 6;
  int l31 = lane & 31, hi = lane >> 5;

  __shared__ short Ks[2][64 * 64];   // [kv][d], 8-elem chunk ^= (kv&7)
  __shared__ short Vs[2][64 * 64];   // [d][kv], 8-elem chunk ^= ((d>>1)&7)

  int qrow = qt * 128 + wave * 32 + l31;
  int qc = qrow < N_ ? qrow : N_ - 1;
  const short* qp = qkv + (size_t)(b * N_ + qc) * 3072 + h * 64;
  v8s qf[4];
#pragma unroll
  for (int i = 0; i < 4; i++) qf[i] = *reinterpret_cast<const v8s*>(qp + i * 16 + hi * 8);

  v16f oa0, oa1;
#pragma unroll
  for (int r = 0; r < 16; r++) { oa0[r] = 0.f; oa1[r] = 0.f; }
  float m = -INFINITY, ls = 0.f;

  // K staging: wave w covers kv rows w*8..+8 (call A) and +32 (call B), chunk = lane&7 pre-swizzled
  int kvA = wave * 8 + (lane >> 3);
  int kchunk = ((lane & 7) ^ (kvA & 7)) << 3;
  // V staging: wave w covers d rows w*16..+8 (call A) and +8 (call B) from vtg, pre-swizzled chunks
  int vdA = wave * 16 + (lane >> 3);
  int vdB = vdA + 8;
  int vchA = ((lane & 7) ^ ((vdA >> 1) & 7)) << 3;
  int vchB = ((lane & 7) ^ ((vdB >> 1) & 7)) << 3;
  const short* vbase = vt + (size_t)bh * 64 * NKV;

#define STAGE_KV(ti, bi)                                                          \
  do {                                                                            \
    int kv0_ = (ti) * 64;                                                         \
    int ra_ = kv0_ + kvA;      ra_ = ra_ < N_ ? ra_ : N_ - 1;                     \
    int rb_ = kv0_ + kvA + 32; rb_ = rb_ < N_ ? rb_ : N_ - 1;                     \
    gl_lds16(qkv + (size_t)(b * N_ + ra_) * 3072 + 1024 + h * 64 + kchunk,        \
             &Ks[bi][wave * 512]);                                                \
    gl_lds16(qkv + (size_t)(b * N_ + rb_) * 3072 + 1024 + h * 64 + kchunk,        \
             &Ks[bi][2048 + wave * 512]);                                         \
    gl_lds16(vbase + (size_t)vdA * NKV + kv0_ + vchA, &Vs[bi][wave * 1024]);      \
    gl_lds16(vbase + (size_t)vdB * NKV + kv0_ + vchB, &Vs[bi][wave * 1024 + 512]);\
  } while (0)

  const int NT = NKV / 64;   // 22
  STAGE_KV(0, 0);
  __syncthreads();
  int bi = 0;
  for (int t = 0; t < NT; ++t) {
    int kv0 = t * 64;
    if (t + 1 < NT) STAGE_KV(t + 1, bi ^ 1);   // loads fly across this tile's compute

    v16f s0, s1;
#pragma unroll
    for (int r = 0; r < 16; r++) { s0[r] = 0.f; s1[r] = 0.f; }
#pragma unroll
    for (int i = 0; i < 4; i++) {
      int c0 = ((2 * i + hi) ^ (l31 & 7)) << 3;
      v8s ka = *reinterpret_cast<const v8s*>(&Ks[bi][l31 * 64 + c0]);
      v8s kb = *reinterpret_cast<const v8s*>(&Ks[bi][(32 + l31) * 64 + c0]);
      s0 = __builtin_amdgcn_mfma_f32_32x32x16_bf16(ka, qf[i], s0, 0, 0, 0);
      s1 = __builtin_amdgcn_mfma_f32_32x32x16_bf16(kb, qf[i], s1, 0, 0, 0);
    }

    if (kv0 + 64 > N_) {
#pragma unroll
      for (int r = 0; r < 16; r++) {
        int crow = (r & 3) + 8 * (r >> 2) + 4 * hi;
        if (kv0 + crow >= N_) s0[r] = -1e30f;
        if (kv0 + 32 + crow >= N_) s1[r] = -1e30f;
      }
    }

    float pmax = s0[0];
#pragma unroll
    for (int r = 1; r < 16; r++) pmax = fmaxf(pmax, s0[r]);
#pragma unroll
    for (int r = 0; r < 16; r++) pmax = fmaxf(pmax, s1[r]);
    pmax = fmaxf(pmax, __shfl_xor(pmax, 32));

    if (!__all(pmax <= m + 11.0f)) {
      float mn = fmaxf(m, pmax);
      float scf = exp2f(m - mn);
      m = mn;
#pragma unroll
      for (int r = 0; r < 16; r++) {
        int crow = (r & 3) + 8 * (r >> 2) + 4 * hi;
        float sv = __shfl(scf, crow);
        oa0[r] *= sv; oa1[r] *= sv;
      }
      ls *= scf;
    }

    float p0[16], p1[16];
    float psum = 0.f;
#pragma unroll
    for (int r = 0; r < 16; r++) { p0[r] = exp2f(s0[r] - m); psum += p0[r]; }
#pragma unroll
    for (int r = 0; r < 16; r++) { p1[r] = exp2f(s1[r] - m); psum += p1[r]; }
    psum += __shfl_xor(psum, 32);
    ls += psum;

    v8s pa0 = pack_swap(p0), pa1 = pack_swap(p0 + 8), pa2 = pack_swap(p1), pa3 = pack_swap(p1 + 8);

#pragma unroll
    for (int i = 0; i < 4; i++) {
      v8s pai = (i == 0) ? pa0 : (i == 1) ? pa1 : (i == 2) ? pa2 : pa3;
      int cc = ((2 * i + hi) ^ ((l31 >> 1) & 7)) << 3;
      v8s v0f = *reinterpret_cast<const v8s*>(&Vs[bi][l31 * 64 + cc]);
      v8s v1f = *reinterpret_cast<const v8s*>(&Vs[bi][(32 + l31) * 64 + cc]);
      oa0 = __builtin_amdgcn_mfma_f32_32x32x16_bf16(pai, v0f, oa0, 0, 0, 0);
      oa1 = __builtin_amdgcn_mfma_f32_32x32x16_bf16(pai, v1f, oa1, 0, 0, 0);
    }
    __syncthreads();   // drains this tile's ds_reads + next tile's gl_lds (vmcnt 0)
    bi ^= 1;
  }
#undef STAGE_KV

  float inv = 1.f / ls;
#pragma unroll
  for (int r = 0; r < 16; r++) {
    int crow = (r & 3) + 8 * (r >> 2) + 4 * hi;
    float iv = __shfl(inv, crow);
    int qg = qt * 128 + wave * 32 + crow;
    if (qg < N_) {
      size_t base = (size_t)(b * N_ + qg) * 1024 + h * 64;
      o[base + l31] = f2bf(oa0[r] * iv);
      o[base + 32 + l31] = f2bf(oa1[r] * iv);
    }
  }
}

extern "C" void kernel_launch(void* const* d_in, const int* in_sizes, int n_in,
                              void* d_out, int out_size, void* d_ws, size_t ws_size,
                              hipStream_t stream) {
  const float* x     = (const float*)d_in[0];
  const float* ln1g  = (const float*)d_in[1];
  const float* ln1b  = (const float*)d_in[2];
  const float* wqkv  = (const float*)d_in[3];
  const float* bqkv  = (const float*)d_in[4];
  const float* wproj = (const float*)d_in[5];
  const float* bproj = (const float*)d_in[6];
  const float* g1    = (const float*)d_in[7];
  const float* ln2g  = (const float*)d_in[8];
  const float* ln2b  = (const float*)d_in[9];
  const float* wfc1  = (const float*)d_in[10];
  const float* bfc1  = (const float*)d_in[11];
  const float* wfc2  = (const float*)d_in[12];
  const float* bfc2  = (const float*)d_in[13];
  const float* g2    = (const float*)d_in[14];
  float* out = (float*)d_out;

  char* p = (char*)d_ws;
  short* wb   = (short*)(p);                 // bf16 weights, 25,165,824 B
  short* h1   = (short*)(p + 25165824);      // bf16 [MPAD][1024]
  short* qkvb = (short*)(p + 36438016);      // bf16 [MPAD][3072]
  short* ob   = (short*)(p + 70254592);      // bf16 [MPAD][1024]
  float* x2   = (float*)(p + 81526784);      // f32  [MPAD][1024]  (end 104,071,168)
  short* vtg  = (short*)x2;                  // bf16 [64][64][NKV] = 11.5 MB, dead before proj writes x2
  short* h2   = ob;                          // reuse (proj consumed ob before LN2)
  short* mlp  = h1;                          // reuse h1+qkvb region: [MPAD][4096] bf16

  cast_w<<<12288, 256, 0, stream>>>(wqkv, wproj, wfc1, wfc2, wb);
  ln_k<<<MPAD, 256, 0, stream>>>(x, ln1g, ln1b, h1, M_);
  gemm_k<0><<<dim3(24, 43), 256, 0, stream>>>(h1, wb, bqkv, nullptr, nullptr, qkvb, nullptr, 1024, 3072, M_);
  vtrans_k<<<dim3(11, 64), 256, 0, stream>>>(qkvb, vtg);
  attn_k<<<dim3(11, 64), 256, 0, stream>>>(qkvb, vtg, ob);
  gemm_k<1><<<dim3(8, 43), 256, 0, stream>>>(ob, wb + 3145728, bproj, x, g1, nullptr, x2, 1024, 1024, M_);
  ln_k<<<MPAD, 256, 0, stream>>>(x2, ln2g, ln2b, h2, M_);
  gemm_k<2><<<dim3(32, 43), 256, 0, stream>>>(h2, wb + 4194304, bfc1, nullptr, nullptr, mlp, nullptr, 1024, 4096, M_);
  gemm_k<1><<<dim3(8, 43), 256, 0, stream>>>(mlp, wb + 8388608, bfc2, x2, g2, nullptr, out, 4096, 1024, M_);
}

// Round 6
// 355.833 us; speedup vs baseline: 1.3678x; 1.0134x over previous
//
#include <hip/hip_runtime.h>
#include <hip/hip_bf16.h>
#include <math.h>

#define B_ 4
#define N_ 1370
#define C_ 1024
#define H_ 16
#define DH_ 64
#define HID_ 4096
#define M_ (B_*N_)      // 5480
#define MPAD 5504       // 43*128 = 86*64
#define NKV 1408        // 22*64 padded kv

typedef short v8s __attribute__((ext_vector_type(8)));
typedef short v4s16 __attribute__((ext_vector_type(4)));
typedef float v4f __attribute__((ext_vector_type(4)));
typedef float v16f __attribute__((ext_vector_type(16)));

__device__ __forceinline__ short f2bf(float x) {
  union { float f; unsigned u; } a; a.f = x;
  unsigned r = (a.u + 0x7fffu + ((a.u >> 16) & 1u)) >> 16;
  return (short)r;
}

__device__ __forceinline__ void gl_lds16(const void* g, void* l) {
  __builtin_amdgcn_global_load_lds(
      (const __attribute__((address_space(1))) unsigned int*)g,
      (__attribute__((address_space(3))) unsigned int*)l, 16, 0, 0);
}

// ---- cast all four weight matrices f32 -> bf16 into one contiguous ws region
__global__ __launch_bounds__(256) void cast_w(const float* __restrict__ wq, const float* __restrict__ wp,
                                              const float* __restrict__ w1, const float* __restrict__ w2,
                                              short* __restrict__ out) {
  int i = blockIdx.x * 256 + threadIdx.x;
  int e = i << 2;
  const float* src; int off;
  if (e < 3145728)      { src = wq; off = e; }
  else if (e < 4194304) { src = wp; off = e - 3145728; }
  else if (e < 8388608) { src = w1; off = e - 4194304; }
  else                  { src = w2; off = e - 8388608; }
  float4 v = *reinterpret_cast<const float4*>(src + off);
  v4s16 o;
  o[0] = f2bf(v.x); o[1] = f2bf(v.y); o[2] = f2bf(v.z); o[3] = f2bf(v.w);
  *reinterpret_cast<v4s16*>(out + e) = o;
}

// ---- layernorm (f32 in, bf16 out), one block per row, pad rows -> zeros
__global__ __launch_bounds__(256) void ln_k(const float* __restrict__ x, const float* __restrict__ g,
                                            const float* __restrict__ bt, short* __restrict__ out, int mreal) {
  int row = blockIdx.x, t = threadIdx.x;
  short* orow = out + (size_t)row * C_;
  if (row >= mreal) {
    v4s16 z = {0,0,0,0};
    reinterpret_cast<v4s16*>(orow)[t] = z;
    return;
  }
  float4 v = reinterpret_cast<const float4*>(x + (size_t)row * C_)[t];
  float s = v.x + v.y + v.z + v.w;
  float q = v.x*v.x + v.y*v.y + v.z*v.z + v.w*v.w;
#pragma unroll
  for (int m = 1; m < 64; m <<= 1) { s += __shfl_xor(s, m); q += __shfl_xor(q, m); }
  __shared__ float sb[8];
  int w = t >> 6;
  if ((t & 63) == 0) { sb[w] = s; sb[4 + w] = q; }
  __syncthreads();
  s = sb[0] + sb[1] + sb[2] + sb[3];
  q = sb[4] + sb[5] + sb[6] + sb[7];
  float mean = s * (1.f / C_);
  float rstd = rsqrtf(q * (1.f / C_) - mean * mean + 1e-5f);
  float4 gv = reinterpret_cast<const float4*>(g)[t];
  float4 bv = reinterpret_cast<const float4*>(bt)[t];
  v4s16 o;
  o[0] = f2bf((v.x - mean) * rstd * gv.x + bv.x);
  o[1] = f2bf((v.y - mean) * rstd * gv.y + bv.y);
  o[2] = f2bf((v.z - mean) * rstd * gv.z + bv.z);
  o[3] = f2bf((v.w - mean) * rstd * gv.w + bv.w);
  reinterpret_cast<v4s16*>(orow)[t] = o;
}

// ---- BMx128-tile bf16 GEMM, 3-buffer counted-vmcnt pipeline (T3+T4+T5)
// 1-D grid, N-major XCD-chunked mapping: each XCD owns whole output columns
// MODE 0: obf = bf16( (v+bias) * (col<1024 ? 0.125*log2e : 1) )   [QKV]
// MODE 1: of32 = resid + gamma*(v+bias)   (rows < mreal)          [proj / fc2]
// MODE 2: obf = bf16( gelu_exact(v+bias) )                        [fc1]
template<int MODE, int BM>
__global__ __launch_bounds__(256) void gemm_k(
    const short* __restrict__ A, const short* __restrict__ Bw,
    const float* __restrict__ bias, const float* __restrict__ resid,
    const float* __restrict__ gamma, short* __restrict__ obf,
    float* __restrict__ of32, int K, int Nc, int mreal, int nTm)
{
  constexpr int MF = BM / 32;                 // m-frags per wave (wave covers BM/2 rows)
  __shared__ short As[3][BM * 32];
  __shared__ short Bs[3][128 * 32];
  int tid = threadIdx.x;
  int lane = tid & 63, wave = tid >> 6;
  int l15 = lane & 15, lhi = lane >> 4;
  int nwg = gridDim.x;
  int sidx = blockIdx.x;
  int ord = (sidx & 7) * (nwg >> 3) + (sidx >> 3);   // XCD-chunked (nwg % 8 == 0)
  int tn = ord / nTm, tm = ord % nTm;                 // N-major: XCD owns columns
  int wr = wave >> 1, wc = wave & 1;

  v4f acc[MF][4];
#pragma unroll
  for (int m = 0; m < MF; m++)
#pragma unroll
    for (int n = 0; n < 4; n++) acc[m][n] = v4f{0.f, 0.f, 0.f, 0.f};

  int lrow = lane >> 2, lch = lane & 3;
  int scol = ((lch ^ ((lrow >> 1) & 3)) << 3);
  const short* Ag = A + (size_t)(tm * BM + wave * 16 + lrow) * K + scol;
  const short* Bg = Bw + (size_t)(tn * 128 + wave * 16 + lrow) * K + scol;
  int fch = ((lhi ^ ((l15 >> 1) & 3)) << 3);

#define STAGE_G(bi, k0)                                                     \
  do {                                                                      \
    gl_lds16(Ag + (k0), &As[bi][wave * 512]);                               \
    if constexpr (BM == 128)                                                \
      gl_lds16(Ag + (size_t)64 * K + (k0), &As[bi][2048 + wave * 512]);     \
    gl_lds16(Bg + (k0), &Bs[bi][wave * 512]);                               \
    gl_lds16(Bg + (size_t)64 * K + (k0), &Bs[bi][2048 + wave * 512]);       \
  } while (0)

  int kT = K >> 5;   // >= 3 always

  STAGE_G(0, 0);
  STAGE_G(1, 1 << 5);
  STAGE_G(2, 2 << 5);

  auto body = [&](int t, int bb, bool stage_next) {
    __builtin_amdgcn_s_barrier();
    v8s af[MF], bfr[4];
#pragma unroll
    for (int m = 0; m < MF; m++)
      af[m] = *reinterpret_cast<const v8s*>(&As[bb][(wr * (BM / 2) + m * 16 + l15) * 32 + fch]);
#pragma unroll
    for (int n = 0; n < 4; n++)
      bfr[n] = *reinterpret_cast<const v8s*>(&Bs[bb][(wc * 64 + n * 16 + l15) * 32 + fch]);
    asm volatile("s_waitcnt lgkmcnt(0)" ::: "memory");
    __builtin_amdgcn_s_barrier();
    if (stage_next) STAGE_G(bb, (t + 3) << 5);
    __builtin_amdgcn_s_setprio(1);
#pragma unroll
    for (int m = 0; m < MF; m++)
#pragma unroll
      for (int n = 0; n < 4; n++)
        acc[m][n] = __builtin_amdgcn_mfma_f32_16x16x32_bf16(af[m], bfr[n], acc[m][n], 0, 0, 0);
    __builtin_amdgcn_s_setprio(0);
  };

  int b = 0, t = 0;
  for (; t < kT - 2; ++t) {
    if constexpr (BM == 128) asm volatile("s_waitcnt vmcnt(8)" ::: "memory");
    else                     asm volatile("s_waitcnt vmcnt(6)" ::: "memory");
    body(t, b, t + 3 < kT);
    b = (b == 2) ? 0 : b + 1;
  }
  if constexpr (BM == 128) asm volatile("s_waitcnt vmcnt(4)" ::: "memory");
  else                     asm volatile("s_waitcnt vmcnt(3)" ::: "memory");
  body(kT - 2, b, false);
  b = (b == 2) ? 0 : b + 1;
  asm volatile("s_waitcnt vmcnt(0)" ::: "memory");
  body(kT - 1, b, false);
#undef STAGE_G

  int row0 = tm * BM + wr * (BM / 2) + (lhi << 2);
  int col0 = tn * 128 + wc * 64 + l15;
#pragma unroll
  for (int m = 0; m < MF; m++) {
#pragma unroll
    for (int n = 0; n < 4; n++) {
      int gc = col0 + n * 16;
      float bb = bias[gc];
      float gm = (MODE == 1) ? gamma[gc] : 0.f;
#pragma unroll
      for (int r = 0; r < 4; r++) {
        int gr = row0 + m * 16 + r;
        float v = acc[m][n][r] + bb;
        if (MODE == 0) {
          float sc = (gc < 1024) ? 0.18033688011112042f : 1.0f;  // 0.125 * log2(e)
          obf[(size_t)gr * Nc + gc] = f2bf(v * sc);
        } else if (MODE == 2) {
          obf[(size_t)gr * Nc + gc] = f2bf(0.5f * v * (1.f + erff(v * 0.70710678f)));
        } else {
          if (gr < mreal) of32[(size_t)gr * Nc + gc] = resid[(size_t)gr * Nc + gc] + gm * v;
        }
      }
    }
  }
}

// ---- V transpose: qkvb V-third [token][2048+h*64+d] -> vtg[(bh*64+d)][kv], kv padded to NKV
__global__ __launch_bounds__(256) void vtrans_k(const short* __restrict__ qkv, short* __restrict__ vt) {
  int kt = blockIdx.x;          // 0..10, 128 kv rows each
  int bh = blockIdx.y;          // 0..63
  int b = bh >> 4, h = bh & 15;
  int t = threadIdx.x;
  __shared__ short T[128][76];
  int n0 = kt * 128;
  int r = t >> 1;
  int c0 = (t & 1) * 32;
  int tok = n0 + r;
  int tokc = tok < N_ ? tok : N_ - 1;
  const short* src = qkv + (size_t)(b * N_ + tokc) * 3072 + 2048 + h * 64 + c0;
  v8s a0 = *reinterpret_cast<const v8s*>(src);
  v8s a1 = *reinterpret_cast<const v8s*>(src + 8);
  v8s a2 = *reinterpret_cast<const v8s*>(src + 16);
  v8s a3 = *reinterpret_cast<const v8s*>(src + 24);
  *reinterpret_cast<v8s*>(&T[r][c0]) = a0;
  *reinterpret_cast<v8s*>(&T[r][c0 + 8]) = a1;
  *reinterpret_cast<v8s*>(&T[r][c0 + 16]) = a2;
  *reinterpret_cast<v8s*>(&T[r][c0 + 24]) = a3;
  __syncthreads();
  int d = t & 63;
  int k0 = (t >> 6) * 32;
  short tmp[32];
#pragma unroll
  for (int j = 0; j < 32; j++) tmp[j] = T[k0 + j][d];
  short* dst = vt + ((size_t)bh * 64 + d) * NKV + n0 + k0;
#pragma unroll
  for (int j = 0; j < 32; j += 8)
    *reinterpret_cast<v8s*>(dst + j) = *reinterpret_cast<const v8s*>(&tmp[j]);
}

// ---- P fragment builder: 8 f32 (C/D-layout regs) -> A-frag via cvt_pk + permlane32_swap (T12)
__device__ __forceinline__ v8s pack_swap(const float* p) {
  unsigned w0, w1, w2, w3;
  asm("v_cvt_pk_bf16_f32 %0, %1, %2" : "=v"(w0) : "v"(p[0]), "v"(p[1]));
  asm("v_cvt_pk_bf16_f32 %0, %1, %2" : "=v"(w1) : "v"(p[2]), "v"(p[3]));
  asm("v_cvt_pk_bf16_f32 %0, %1, %2" : "=v"(w2) : "v"(p[4]), "v"(p[5]));
  asm("v_cvt_pk_bf16_f32 %0, %1, %2" : "=v"(w3) : "v"(p[6]), "v"(p[7]));
  asm("v_permlane32_swap_b32 %0, %1" : "+v"(w0), "+v"(w2));
  asm("v_permlane32_swap_b32 %0, %1" : "+v"(w1), "+v"(w3));
  union { unsigned u[4]; v8s s; } r;
  r.u[0] = w0; r.u[1] = w1; r.u[2] = w2; r.u[3] = w3;
  return r.s;
}

// ---- flash attention, swapped-QK^T 32x32x16, K+V gl_lds double-buffer, 1 barrier/tile
__global__ __launch_bounds__(256) void attn_k(const short* __restrict__ qkv, const short* __restrict__ vt,
                                              short* __restrict__ o)
{
  int s = blockIdx.x + 11 * blockIdx.y;
  int ord = (s & 7) * 88 + (s >> 3);
  int qt = ord % 11, bh = ord / 11;
  int b = bh >> 4, h = bh & 15;
  int tid = threadIdx.x;
  int lane = tid & 63, wave = tid >> 6;
  int l31 = lane & 31, hi = lane >> 5;

  __shared__ short Ks[2][64 * 64];   // [kv][d], 8-elem chunk ^= (kv&7)
  __shared__ short Vs[2][64 * 64];   // [d][kv], 8-elem chunk ^= ((d>>1)&7)

  int qrow = qt * 128 + wave * 32 + l31;
  int qc = qrow < N_ ? qrow : N_ - 1;
  const short* qp = qkv + (size_t)(b * N_ + qc) * 3072 + h * 64;
  v8s qf[4];
#pragma unroll
  for (int i = 0; i < 4; i++) qf[i] = *reinterpret_cast<const v8s*>(qp + i * 16 + hi * 8);

  v16f oa0, oa1;
#pragma unroll
  for (int r = 0; r < 16; r++) { oa0[r] = 0.f; oa1[r] = 0.f; }
  float m = -INFINITY, ls = 0.f;

  int kvA = wave * 8 + (lane >> 3);
  int kchunk = ((lane & 7) ^ (kvA & 7)) << 3;
  int vdA = wave * 16 + (lane >> 3);
  int vdB = vdA + 8;
  int vchA = ((lane & 7) ^ ((vdA >> 1) & 7)) << 3;
  int vchB = ((lane & 7) ^ ((vdB >> 1) & 7)) << 3;
  const short* vbase = vt + (size_t)bh * 64 * NKV;

#define STAGE_KV(ti, bi)                                                          \
  do {                                                                            \
    int kv0_ = (ti) * 64;                                                         \
    int ra_ = kv0_ + kvA;      ra_ = ra_ < N_ ? ra_ : N_ - 1;                     \
    int rb_ = kv0_ + kvA + 32; rb_ = rb_ < N_ ? rb_ : N_ - 1;                     \
    gl_lds16(qkv + (size_t)(b * N_ + ra_) * 3072 + 1024 + h * 64 + kchunk,        \
             &Ks[bi][wave * 512]);                                                \
    gl_lds16(qkv + (size_t)(b * N_ + rb_) * 3072 + 1024 + h * 64 + kchunk,        \
             &Ks[bi][2048 + wave * 512]);                                         \
    gl_lds16(vbase + (size_t)vdA * NKV + kv0_ + vchA, &Vs[bi][wave * 1024]);      \
    gl_lds16(vbase + (size_t)vdB * NKV + kv0_ + vchB, &Vs[bi][wave * 1024 + 512]);\
  } while (0)

  const int NT = NKV / 64;   // 22
  STAGE_KV(0, 0);
  __syncthreads();
  int bi = 0;
  for (int t = 0; t < NT; ++t) {
    int kv0 = t * 64;
    if (t + 1 < NT) STAGE_KV(t + 1, bi ^ 1);

    v16f s0, s1;
#pragma unroll
    for (int r = 0; r < 16; r++) { s0[r] = 0.f; s1[r] = 0.f; }
#pragma unroll
    for (int i = 0; i < 4; i++) {
      int c0 = ((2 * i + hi) ^ (l31 & 7)) << 3;
      v8s ka = *reinterpret_cast<const v8s*>(&Ks[bi][l31 * 64 + c0]);
      v8s kb = *reinterpret_cast<const v8s*>(&Ks[bi][(32 + l31) * 64 + c0]);
      s0 = __builtin_amdgcn_mfma_f32_32x32x16_bf16(ka, qf[i], s0, 0, 0, 0);
      s1 = __builtin_amdgcn_mfma_f32_32x32x16_bf16(kb, qf[i], s1, 0, 0, 0);
    }

    if (kv0 + 64 > N_) {
#pragma unroll
      for (int r = 0; r < 16; r++) {
        int crow = (r & 3) + 8 * (r >> 2) + 4 * hi;
        if (kv0 + crow >= N_) s0[r] = -1e30f;
        if (kv0 + 32 + crow >= N_) s1[r] = -1e30f;
      }
    }

    float pmax = s0[0];
#pragma unroll
    for (int r = 1; r < 16; r++) pmax = fmaxf(pmax, s0[r]);
#pragma unroll
    for (int r = 0; r < 16; r++) pmax = fmaxf(pmax, s1[r]);
    pmax = fmaxf(pmax, __shfl_xor(pmax, 32));

    if (!__all(pmax <= m + 11.0f)) {
      float mn = fmaxf(m, pmax);
      float scf = exp2f(m - mn);
      m = mn;
#pragma unroll
      for (int r = 0; r < 16; r++) {
        int crow = (r & 3) + 8 * (r >> 2) + 4 * hi;
        float sv = __shfl(scf, crow);
        oa0[r] *= sv; oa1[r] *= sv;
      }
      ls *= scf;
    }

    float p0[16], p1[16];
    float psum = 0.f;
#pragma unroll
    for (int r = 0; r < 16; r++) { p0[r] = exp2f(s0[r] - m); psum += p0[r]; }
#pragma unroll
    for (int r = 0; r < 16; r++) { p1[r] = exp2f(s1[r] - m); psum += p1[r]; }
    psum += __shfl_xor(psum, 32);
    ls += psum;

    v8s pa0 = pack_swap(p0), pa1 = pack_swap(p0 + 8), pa2 = pack_swap(p1), pa3 = pack_swap(p1 + 8);

#pragma unroll
    for (int i = 0; i < 4; i++) {
      v8s pai = (i == 0) ? pa0 : (i == 1) ? pa1 : (i == 2) ? pa2 : pa3;
      int cc = ((2 * i + hi) ^ ((l31 >> 1) & 7)) << 3;
      v8s v0f = *reinterpret_cast<const v8s*>(&Vs[bi][l31 * 64 + cc]);
      v8s v1f = *reinterpret_cast<const v8s*>(&Vs[bi][(32 + l31) * 64 + cc]);
      oa0 = __builtin_amdgcn_mfma_f32_32x32x16_bf16(pai, v0f, oa0, 0, 0, 0);
      oa1 = __builtin_amdgcn_mfma_f32_32x32x16_bf16(pai, v1f, oa1, 0, 0, 0);
    }
    __syncthreads();
    bi ^= 1;
  }
#undef STAGE_KV

  float inv = 1.f / ls;
#pragma unroll
  for (int r = 0; r < 16; r++) {
    int crow = (r & 3) + 8 * (r >> 2) + 4 * hi;
    float iv = __shfl(inv, crow);
    int qg = qt * 128 + wave * 32 + crow;
    if (qg < N_) {
      size_t base = (size_t)(b * N_ + qg) * 1024 + h * 64;
      o[base + l31] = f2bf(oa0[r] * iv);
      o[base + 32 + l31] = f2bf(oa1[r] * iv);
    }
  }
}

extern "C" void kernel_launch(void* const* d_in, const int* in_sizes, int n_in,
                              void* d_out, int out_size, void* d_ws, size_t ws_size,
                              hipStream_t stream) {
  const float* x     = (const float*)d_in[0];
  const float* ln1g  = (const float*)d_in[1];
  const float* ln1b  = (const float*)d_in[2];
  const float* wqkv  = (const float*)d_in[3];
  const float* bqkv  = (const float*)d_in[4];
  const float* wproj = (const float*)d_in[5];
  const float* bproj = (const float*)d_in[6];
  const float* g1    = (const float*)d_in[7];
  const float* ln2g  = (const float*)d_in[8];
  const float* ln2b  = (const float*)d_in[9];
  const float* wfc1  = (const float*)d_in[10];
  const float* bfc1  = (const float*)d_in[11];
  const float* wfc2  = (const float*)d_in[12];
  const float* bfc2  = (const float*)d_in[13];
  const float* g2    = (const float*)d_in[14];
  float* out = (float*)d_out;

  char* p = (char*)d_ws;
  short* wb   = (short*)(p);                 // bf16 weights, 25,165,824 B
  short* h1   = (short*)(p + 25165824);      // bf16 [MPAD][1024]
  short* qkvb = (short*)(p + 36438016);      // bf16 [MPAD][3072]
  short* ob   = (short*)(p + 70254592);      // bf16 [MPAD][1024]
  float* x2   = (float*)(p + 81526784);      // f32  [MPAD][1024]  (end 104,071,168)
  short* vtg  = (short*)x2;                  // bf16 [64][64][NKV] = 11.5 MB, dead before proj writes x2
  short* h2   = ob;                          // reuse (proj consumed ob before LN2)
  short* mlp  = h1;                          // reuse h1+qkvb region: [MPAD][4096] bf16

  cast_w<<<12288, 256, 0, stream>>>(wqkv, wproj, wfc1, wfc2, wb);
  ln_k<<<MPAD, 256, 0, stream>>>(x, ln1g, ln1b, h1, M_);
  gemm_k<0, 128><<<1032, 256, 0, stream>>>(h1, wb, bqkv, nullptr, nullptr, qkvb, nullptr, 1024, 3072, M_, 43);
  vtrans_k<<<dim3(11, 64), 256, 0, stream>>>(qkvb, vtg);
  attn_k<<<dim3(11, 64), 256, 0, stream>>>(qkvb, vtg, ob);
  gemm_k<1, 64><<<688, 256, 0, stream>>>(ob, wb + 3145728, bproj, x, g1, nullptr, x2, 1024, 1024, M_, 86);
  ln_k<<<MPAD, 256, 0, stream>>>(x2, ln2g, ln2b, h2, M_);
  gemm_k<2, 128><<<1376, 256, 0, stream>>>(h2, wb + 4194304, bfc1, nullptr, nullptr, mlp, nullptr, 1024, 4096, M_, 43);
  gemm_k<1, 64><<<688, 256, 0, stream>>>(mlp, wb + 8388608, bfc2, x2, g2, nullptr, out, 4096, 1024, M_, 86);
}